// Round 5
// baseline (556.888 us; speedup 1.0000x reference)
//
#include <hip/hip_runtime.h>
#include <math.h>
#include <stdint.h>

// AttnEmo: B=8, S=T=2048, E=512. All-MFMA, fixed-shift unnormalized softmax.
// R12 (on R11, which FAILED):
//  - R11 bug: mask pack covered only 1/4 of the mask (4 int4/thread; needed
//    16). Batches 1-7 read stale garbage -> absmax 5.5.
//  - Fix: 16 int4/thread (exact: 2048 blk x 4096 int4 = 33.5M ints), and
//    packed format switched to BALLOT-NATURAL order: for 256-int group G,
//    word G*4+j bit l = mask[G*256 + 4l + j]. Prepass stores 4 ballots/round
//    directly (no bit-interleave VALU); logits epilogue extracts with the
//    matching permutation: word = rowG*4 + (fr&3), bit = ((c0&255)>>2)
//    + (fr>>2) + 4j.  (We control both sides of the format.)
//  - prepass reads stay fully lane-coalesced (1KB contiguous per wave instr),
//    batched deep (8 float4 + 16 int4 issued before use).
// R8-R10: mask bit-packed once (134MB int32 -> 4.2MB bits in dead k_lo);
//     logits epilogue reads L2/L3-hot words instead of 64 HBM loads/lane.
// Tiled layout: chunk(row,k) at (row>>4)*16*ld + (k>>3)*128 + (row&15)*8+(k&7)
//  -> gld16 staging lane l fetches base+l*16 (1KB contiguous), lands in
//     fragment order, ds_read base+lane*16, zero bank conflicts (R6-proven).

#define BB 8
#define SS 2048
#define TT 2048
#define EE 512

typedef __attribute__((ext_vector_type(8))) short short8;
typedef __attribute__((ext_vector_type(4))) short short4v;
typedef __attribute__((ext_vector_type(4))) float f32x4;

__device__ __forceinline__ uint16_t f2bf(float f) {      // RNE fp32->bf16
  uint32_t u = __builtin_bit_cast(uint32_t, f);
  u += 0x7fffu + ((u >> 16) & 1u);
  return (uint16_t)(u >> 16);
}
__device__ __forceinline__ float bf2f(uint16_t h) {
  uint32_t u = ((uint32_t)h) << 16;
  return __builtin_bit_cast(float, u);
}

// tiled element offset (ld = row length in elements, multiple of 8)
__device__ __forceinline__ size_t toff(int row, int col, int ld) {
  return (size_t)(row >> 4) * ((size_t)ld << 4) + ((size_t)(col >> 3) << 7)
       + ((row & 15) << 3) + (col & 7);
}

// async global->LDS, 16B per lane; LDS dest = wave-uniform base + lane*16
__device__ __forceinline__ void gld16(const void* g, void* l) {
  __builtin_amdgcn_global_load_lds(
      (const __attribute__((address_space(1))) void*)g,
      (__attribute__((address_space(3))) void*)l, 16, 0, 0);
}

// ---------------------------------------------------------------------------
// NT MFMA GEMM: C[m,n] = sum_k A[m,k]*B[n,k]  (both K-major, TILED layout)
// ASRC: 0 = bf16 hi+lo arrays   1 = bf16 hi only
// BSRC: 0 = bf16 hi+lo arrays   1 = bf16 hi only
//   terms: A0/B0 -> 3 (hh, hl, lh);  A0/B1 -> 2 (hh, lh);  A1/B1 -> 1
// EPI:  0 = +biasz[col], split bf16 out tiled (Cp=hi, C2=lo; lo only z==0)
//       1 = +bias[row], bf16 out tiled                        (vT proj)
//       4 = +resid, fp32 out ROW-MAJOR                        (Wo + residual)
//       5 = packed mask -> P_u=exp(L-60) bf16 tiled + atomicAdd row-sum -> sZ
//       6 = val / sZ[row], bf16 out tiled                     (PV normalize)
// WN: wave n-tiles (4 -> 128-wide block). M-tile = 128. 256 threads.
// ---------------------------------------------------------------------------
template<int ASRC, int BSRC, int EPI, int WN>
__global__ __launch_bounds__(256, 2) void mgemm(
    const void* __restrict__ Ap, const void* __restrict__ Alo,
    const void* __restrict__ Bp, const void* __restrict__ Blo,
    void* __restrict__ Cp, void* __restrict__ C2,
    const float* __restrict__ bias, const float* __restrict__ bias2,
    const float* __restrict__ resid,
    const int* __restrict__ mask, float* __restrict__ sZ,
    int K, int lda, int ldb, int ldc,
    size_t sA, size_t sB, size_t sC, size_t sM)
{
  constexpr bool ALOARR = (ASRC == 0);
  constexpr bool BLOARR = (BSRC == 0);
  constexpr bool T3     = (ASRC == 0) && (BSRC == 0);
  constexpr bool T2     = (ASRC == 0) && (BSRC == 1);
  constexpr int  BN     = 32 * WN;
  constexpr int  ABYTES = ALOARR ? 16384 : 8192;
  constexpr int  BBYTES = BLOARR ? BN * 128 : BN * 64;

  __shared__ char smem[ABYTES + BBYTES];

  const int tid  = threadIdx.x;
  const int lane = tid & 63, wv = tid >> 6;
  const int z    = blockIdx.z;
  const int bm   = blockIdx.y * 128;
  const int bn   = blockIdx.x * BN;
  const int fr   = lane & 15;            // fragment row/col
  const int wm   = (wv & 1) * 64;
  const int wn   = (wv >> 1) * (16 * WN);

  const f32x4 zero = {0.f, 0.f, 0.f, 0.f};
  f32x4 acc[4][WN];
#pragma unroll
  for (int i = 0; i < 4; ++i)
#pragma unroll
    for (int j = 0; j < WN; ++j) acc[i][j] = zero;

  // tiled layout: staging lane l's offset within a (16-row x 32-k) seg-tile
  // is just l*8 elements (l*16 bytes) -- fully contiguous per gld16.
  const size_t loff = (size_t)lane * 8;
  const uint16_t* gAh = (const uint16_t*)Ap + sA * z + (size_t)(bm >> 4) * 16 * lda + loff;
  const uint16_t* gAl = ALOARR ? (const uint16_t*)Alo + sA * z + (size_t)(bm >> 4) * 16 * lda + loff : nullptr;
  const uint16_t* gBh = (const uint16_t*)Bp + sB * z + (size_t)(bn >> 4) * 16 * ldb + loff;
  const uint16_t* gBl = BLOARR ? (const uint16_t*)Blo + sB * z + (size_t)(bn >> 4) * 16 * ldb + loff : nullptr;

  for (int k0 = 0; k0 < K; k0 += 32) {
    const size_t ka = (size_t)k0 * 16;           // (k0>>3)*128 elements
    __syncthreads();                       // previous tiles fully consumed
    // ---- stage A (8 segs x 1KB each) ----
#pragma unroll
    for (int t = 0; t < 2; ++t) { int s = wv + t * 4;
      gld16(gAh + (size_t)s * 16 * lda + ka, &smem[s * 1024]); }
    if constexpr (ALOARR) {
#pragma unroll
      for (int t = 0; t < 2; ++t) { int s = wv + t * 4;
        gld16(gAl + (size_t)s * 16 * lda + ka, &smem[8192 + s * 1024]); }
    }
    // ---- stage B ----
#pragma unroll
    for (int t = 0; t < WN / 2; ++t) { int s = wv + t * 4;
      gld16(gBh + (size_t)s * 16 * ldb + ka, &smem[ABYTES + s * 1024]); }
    if constexpr (BLOARR) {
#pragma unroll
      for (int t = 0; t < WN / 2; ++t) { int s = wv + t * 4;
        gld16(gBl + (size_t)s * 16 * ldb + ka, &smem[ABYTES + BN * 64 + s * 1024]); }
    }
    __syncthreads();                       // staging landed

    // ---- fragments: each wave reads base + lane*16 (conflict-free) ----
    short8 ah[4], bh[WN], al_[4], bl_[WN];
#pragma unroll
    for (int i = 0; i < 4; ++i) {
      const char* p = smem + ((wm >> 4) + i) * 1024 + (lane << 4);
      ah[i] = *(const short8*)p;
      if constexpr (ALOARR) al_[i] = *(const short8*)(p + 8192);
    }
#pragma unroll
    for (int j = 0; j < WN; ++j) {
      const char* p = smem + ABYTES + ((wn >> 4) + j) * 1024 + (lane << 4);
      bh[j] = *(const short8*)p;
      if constexpr (BLOARR) bl_[j] = *(const short8*)(p + BN * 64);
    }
    // ---- MFMA ----
#pragma unroll
    for (int i = 0; i < 4; ++i)
#pragma unroll
      for (int j = 0; j < WN; ++j) {
        acc[i][j] = __builtin_amdgcn_mfma_f32_16x16x32_bf16(ah[i], bh[j], acc[i][j], 0, 0, 0);
        if constexpr (T3) {
          acc[i][j] = __builtin_amdgcn_mfma_f32_16x16x32_bf16(ah[i], bl_[j], acc[i][j], 0, 0, 0);
          acc[i][j] = __builtin_amdgcn_mfma_f32_16x16x32_bf16(al_[i], bh[j], acc[i][j], 0, 0, 0);
        } else if constexpr (T2) {
          acc[i][j] = __builtin_amdgcn_mfma_f32_16x16x32_bf16(al_[i], bh[j], acc[i][j], 0, 0, 0);
        }
      }
  }

  // ---- epilogue: C/D layout col=lane&15, row=(lane>>4)*4+reg ----
  if constexpr (EPI == 5) {
    // mask PACKED in ballot-natural order: for 256-int group G (= flat/256),
    // word G*4+j' bit l = (mask int G*256 + 4l + j') != 0.
    // For this wave's 64-col span c0 = bn+wn (64-aligned):
    //   col = c0 + j*16 + fr  ->  word = rowG*4 + (fr&3),
    //   bit = ((c0&255)>>2) + (fr>>2) + 4j.   (rowG = z*16384 + row*8 + c0>>8)
    const unsigned long long* __restrict__ mb = (const unsigned long long*)mask;
    const int c0 = bn + wn;
    const int sh = ((c0 & 255) >> 2) + (fr >> 2);
    const size_t mbase = (size_t)z * 65536 + (size_t)((c0 >> 8) << 2) + (fr & 3);
    unsigned long long mw[4][4];
#pragma unroll
    for (int i = 0; i < 4; ++i)
#pragma unroll
      for (int g = 0; g < 4; ++g) {
        const int row = bm + wm + i * 16 + (lane >> 4) * 4 + g;
        mw[i][g] = mb[mbase + (size_t)row * 32];
      }
#pragma unroll
    for (int i = 0; i < 4; ++i) {
      const int row0 = bm + wm + i * 16 + (lane >> 4) * 4;
#pragma unroll
      for (int g = 0; g < 4; ++g) {
        const int row = row0 + g;
        float rs = 0.f;
#pragma unroll
        for (int j = 0; j < WN; ++j) {
          const int col = bn + wn + j * 16 + fr;
          const bool msk = (mw[i][g] >> (sh + j * 4)) & 1ull;
          const float e = msk ? 0.f : __expf(acc[i][j][g] - 60.0f);
          ((uint16_t*)Cp)[sC * z + toff(row, col, ldc)] = f2bf(e);
          rs += e;
        }
        rs += __shfl_xor(rs, 1);
        rs += __shfl_xor(rs, 2);
        rs += __shfl_xor(rs, 4);
        rs += __shfl_xor(rs, 8);
        if ((lane & 15) == 0) atomicAdd(&sZ[(size_t)z * SS + row], rs);
      }
    }
  } else {
#pragma unroll
    for (int i = 0; i < 4; ++i) {
      const int row0 = bm + wm + i * 16 + (lane >> 4) * 4;
#pragma unroll
      for (int g = 0; g < 4; ++g) {
        const int row = row0 + g;
        float invZ = 1.0f;
        if constexpr (EPI == 6) invZ = 1.0f / sZ[(size_t)z * SS + row];
#pragma unroll
        for (int j = 0; j < WN; ++j) {
          const int col = bn + wn + j * 16 + fr;
          float v = acc[i][j][g];
          if constexpr (EPI == 0) {
            const float* bp = (z == 0) ? bias : bias2;
            const size_t ci = sC * z + toff(row, col, ldc);
            v += bp[col];
            uint16_t h = f2bf(v);
            ((uint16_t*)Cp)[ci] = h;
            // lo term only consumed for q (z==0); k_lo region now holds
            // the packed mask bits -- must NOT be written.
            if (z == 0) ((uint16_t*)C2)[ci] = f2bf(v - bf2f(h));
          } else if constexpr (EPI == 1) {
            v += bias[row];
            ((uint16_t*)Cp)[sC * z + toff(row, col, ldc)] = f2bf(v);
          } else if constexpr (EPI == 4) {
            v += resid[(size_t)row * ldc + col];
            ((float*)Cp)[sC * z + (size_t)row * ldc + col] = v;
          } else {  // EPI == 6
            ((uint16_t*)Cp)[sC * z + toff(row, col, ldc)] = f2bf(v * invZ);
          }
        }
      }
    }
  }
}

// ---------------- fp32 [Rx512] row-major -> hi/lo bf16 TILED ---------------
// Core: one block = 16 rows x 128 cols = 2048 elements. (weights only)
__device__ __forceinline__ void split_core(
    const float* __restrict__ x, uint16_t* __restrict__ hi,
    uint16_t* __restrict__ lo, int bid)
{
  __shared__ uint16_t lh[256 * 8 + 16 * 8];   // 16B chunks, 16B pad per 16
  __shared__ uint16_t ll[256 * 8 + 16 * 8];
  const int t   = threadIdx.x;
  const int seg = bid >> 2, q = bid & 3;

  const float* src = x + (size_t)(seg * 16 + (t >> 4)) * 512 + q * 128 + (t & 15) * 8;
  float4 a = *(const float4*)src;
  float4 b = *(const float4*)(src + 4);
  float v[8] = {a.x, a.y, a.z, a.w, b.x, b.y, b.z, b.w};

  const int slot = (t & 15) * 16 + (t >> 4);
  uint16_t* ph = lh + slot * 8 + (slot >> 4) * 8;
  uint16_t* pl = ll + slot * 8 + (slot >> 4) * 8;
#pragma unroll
  for (int e = 0; e < 8; ++e) {
    uint16_t h = f2bf(v[e]);
    ph[e] = h;
    pl[e] = f2bf(v[e] - bf2f(h));
  }
  __syncthreads();

  const uint16_t* qh = lh + t * 8 + (t >> 4) * 8;
  const uint16_t* ql = ll + t * 8 + (t >> 4) * 8;
  const size_t off = (size_t)seg * 8192 + (size_t)(q * 16 + (t >> 4)) * 128 + (t & 15) * 8;
  *(short8*)(hi + off) = *(const short8*)qh;
  *(short8*)(lo + off) = *(const short8*)ql;
}

// ---------------- coalesced streaming prepass: split + mask pack -----------
// Grid: exactly 2048 blocks x 256 threads. No LDS, no barriers.
// All reads lane-coalesced (1KB contiguous per wave-instr), batched deep.
// blocks 0-1023: enc; 1024-2047: emo. 2048*256*8 float4 = enc+emo exactly;
// 2048*4096 int4 = 33.5M ints = mask exactly (16 int4/thread).
__global__ __launch_bounds__(256) void prepass(
    const float* __restrict__ enc, const float* __restrict__ emo,
    uint16_t* __restrict__ hi, uint16_t* __restrict__ lo, size_t stride,
    const int* __restrict__ mask, unsigned long long* __restrict__ mbits)
{
  const int t    = threadIdx.x;
  const int lane = t & 63, wv = t >> 6;
  const int arr  = blockIdx.x >> 10;              // 0: enc, 1: emo
  const int lb   = blockIdx.x & 1023;             // local block within array

  // ---- issue loads (deep in-flight, fully coalesced) ----
  const float* src = (arr ? emo : enc);
  float4 f[8];
#pragma unroll
  for (int r = 0; r < 8; ++r)
    f[r] = *((const float4*)src + (size_t)lb * 2048 + r * 256 + t);

  const int4* mp = (const int4*)mask + (size_t)blockIdx.x * 4096;
  int4 m[16];
#pragma unroll
  for (int r = 0; r < 16; ++r)
    m[r] = mp[r * 256 + t];

  // ---- split: each float4 = 4 consecutive k of one row -> short4 hi/lo ----
  uint16_t* hp = hi + (size_t)arr * stride;
  uint16_t* lp = lo + (size_t)arr * stride;
#pragma unroll
  for (int r = 0; r < 8; ++r) {
    const int lf  = lb * 2048 + r * 256 + t;      // float4 index within array
    const int row = lf >> 7;                      // 128 float4 per 512-row
    const int k   = (lf & 127) * 4;
    const size_t off = (size_t)(row >> 4) * 8192 + (size_t)(k >> 3) * 128
                     + (row & 15) * 8 + (k & 7);
    const float v[4] = {f[r].x, f[r].y, f[r].z, f[r].w};
    short4v hv, lv;
#pragma unroll
    for (int e = 0; e < 4; ++e) {
      const uint16_t h = f2bf(v[e]);
      hv[e] = (short)h;
      lv[e] = (short)f2bf(v[e] - bf2f(h));
    }
    *(short4v*)(hp + off) = hv;
    *(short4v*)(lp + off) = lv;
  }

  // ---- mask pack, ballot-natural order ----
  // Round r: wave covers 256 consecutive ints (group G = blk*64 + r*4 + wv);
  // ballot of component j = word G*4+j (bit l = int G*256 + 4l + j).
#pragma unroll
  for (int r = 0; r < 16; ++r) {
    const unsigned long long b0 = __ballot(m[r].x != 0);
    const unsigned long long b1 = __ballot(m[r].y != 0);
    const unsigned long long b2 = __ballot(m[r].z != 0);
    const unsigned long long b3 = __ballot(m[r].w != 0);
    if (lane < 4) {
      const unsigned long long w = (lane == 0) ? b0 : (lane == 1) ? b1
                                 : (lane == 2) ? b2 : b3;
      mbits[(size_t)blockIdx.x * 256 + r * 16 + wv * 4 + lane] = w;
    }
  }
}

// 4 weight matrices in one launch: grid 512 (128 each); hi/lo bufs contiguous
__global__ __launch_bounds__(256) void split_w4(
    const float* __restrict__ x0, const float* __restrict__ x1,
    const float* __restrict__ x2, const float* __restrict__ x3,
    uint16_t* __restrict__ hi0, uint16_t* __restrict__ lo0, size_t stride)
{
  const int w   = blockIdx.x >> 7;
  const int bid = blockIdx.x & 127;
  const float* x = (w == 0) ? x0 : (w == 1) ? x1 : (w == 2) ? x2 : x3;
  split_core(x, hi0 + w * stride, lo0 + w * stride, bid);
}

// ---------------- fused LayerNorm epilogue (in-place safe) -----------------
__global__ __launch_bounds__(256) void ln_kernel(
    const float* __restrict__ X, const float* __restrict__ enc,
    const float* __restrict__ gamma, const float* __restrict__ beta,
    float* __restrict__ out)
{
  const int row = blockIdx.x * 4 + (threadIdx.x >> 6);
  const int lane = threadIdx.x & 63;
  const size_t base = (size_t)row * EE;
  const int o0 = lane * 4, o1 = 256 + lane * 4;

  float4 x0 = *(const float4*)(X + base + o0);
  float4 x1 = *(const float4*)(X + base + o1);
  float s = x0.x + x0.y + x0.z + x0.w + x1.x + x1.y + x1.z + x1.w;
#pragma unroll
  for (int off = 32; off > 0; off >>= 1) s += __shfl_xor(s, off);
  const float mean = s * (1.0f / 512.0f);

  float d[8] = {x0.x - mean, x0.y - mean, x0.z - mean, x0.w - mean,
                x1.x - mean, x1.y - mean, x1.z - mean, x1.w - mean};
  float s2 = 0.f;
#pragma unroll
  for (int i = 0; i < 8; ++i) s2 = fmaf(d[i], d[i], s2);
#pragma unroll
  for (int off = 32; off > 0; off >>= 1) s2 += __shfl_xor(s2, off);
  const float stdv = sqrtf(s2 * (1.0f / 512.0f));
  const float inv = 1.0f / (stdv + 1e-6f);

  float4 g0 = *(const float4*)(gamma + o0);
  float4 g1 = *(const float4*)(gamma + o1);
  float4 b0 = *(const float4*)(beta + o0);
  float4 b1 = *(const float4*)(beta + o1);
  float4 e0 = *(const float4*)(enc + base + o0);
  float4 e1 = *(const float4*)(enc + base + o1);

  float4 r0, r1;
  r0.x = e0.x + g0.x * d[0] * inv + b0.x;
  r0.y = e0.y + g0.y * d[1] * inv + b0.y;
  r0.z = e0.z + g0.z * d[2] * inv + b0.z;
  r0.w = e0.w + g0.w * d[3] * inv + b0.w;
  r1.x = e1.x + g1.x * d[4] * inv + b1.x;
  r1.y = e1.y + g1.y * d[5] * inv + b1.y;
  r1.z = e1.z + g1.z * d[6] * inv + b1.z;
  r1.w = e1.w + g1.w * d[7] * inv + b1.w;
  *(float4*)(out + base + o0) = r0;
  *(float4*)(out + base + o1) = r1;
}

extern "C" void kernel_launch(void* const* d_in, const int* in_sizes, int n_in,
                              void* d_out, int out_size, void* d_ws, size_t ws_size,
                              hipStream_t stream) {
  const float* enc   = (const float*)d_in[0];
  const float* emo   = (const float*)d_in[1];
  const int*   mask  = (const int*)d_in[2];
  const float* Wq    = (const float*)d_in[3];
  const float* bq    = (const float*)d_in[4];
  const float* Wk    = (const float*)d_in[5];
  const float* bk    = (const float*)d_in[6];
  const float* Wv    = (const float*)d_in[7];
  const float* bv    = (const float*)d_in[8];
  const float* Wo    = (const float*)d_in[9];
  const float* gamma = (const float*)d_in[10];
  const float* beta  = (const float*)d_in[11];
  float* out = (float*)d_out;
  char*  ws  = (char*)d_ws;

  const size_t SZ = (size_t)BB * SS * EE;   // 8,388,608
  size_t off = 0;
  // adjacency matters: (enc_h,enc_l,emo_h,emo_l) stride 2SZ for fused QK A;
  // (q_hi,q_lo,k_hi,k_lo) stride 2SZ for fused QK C;
  // (wq_h,wq_l,wk_h,wk_l,...) stride 2*EE*EE for fused QK B and split_w4.
  uint16_t* enc_h = (uint16_t*)(ws + off); off += SZ * 2;
  uint16_t* enc_l = (uint16_t*)(ws + off); off += SZ * 2;
  uint16_t* emo_h = (uint16_t*)(ws + off); off += SZ * 2;
  uint16_t* emo_l = (uint16_t*)(ws + off); off += SZ * 2;
  uint16_t* q_hi  = (uint16_t*)(ws + off); off += SZ * 2;
  uint16_t* q_lo  = (uint16_t*)(ws + off); off += SZ * 2;
  uint16_t* k_hi  = (uint16_t*)(ws + off); off += SZ * 2;
  uint16_t* k_lo  = (uint16_t*)(ws + off); off += SZ * 2;  // holds packed mask
  uint16_t* vT    = (uint16_t*)(ws + off); off += SZ * 2;   // [E][B*T] tiled
  uint16_t* ctx   = (uint16_t*)(ws + off); off += SZ * 2;   // [B*S][E] tiled
  uint16_t* wq_h  = (uint16_t*)(ws + off); off += EE * EE * 2;
  uint16_t* wq_l  = (uint16_t*)(ws + off); off += EE * EE * 2;
  uint16_t* wk_h  = (uint16_t*)(ws + off); off += EE * EE * 2;
  uint16_t* wk_l  = (uint16_t*)(ws + off); off += EE * EE * 2;
  uint16_t* wv_h  = (uint16_t*)(ws + off); off += EE * EE * 2;
  uint16_t* wv_l  = (uint16_t*)(ws + off); off += EE * EE * 2;
  uint16_t* wo_h  = (uint16_t*)(ws + off); off += EE * EE * 2;
  uint16_t* wo_l  = (uint16_t*)(ws + off); off += EE * EE * 2;
  uint16_t* P_u   = (uint16_t*)(ws + off); off += (size_t)BB * SS * TT * 2;  // 67MB
  float*    sZ    = (float*)(ws + off);    off += (size_t)BB * SS * 4;
  (void)wk_l; (void)wv_l; (void)wo_l;

  // packed mask bits live in the (otherwise dead) k_lo region: 4.2MB of 16.8MB
  unsigned long long* mbits = (unsigned long long*)k_lo;

  const dim3 blk(256);

  // weights split + coalesced streaming prepass (enc/emo split + mask pack)
  split_w4<<<dim3(512), blk, 0, stream>>>(Wq, Wk, Wv, Wo, wq_h, wq_l,
                                          (size_t)2 * EE * EE);
  prepass<<<dim3(2048), blk, 0, stream>>>(enc, emo, enc_h, enc_l,
                                          (size_t)2 * SZ, mask, mbits);
  hipMemsetAsync(sZ, 0, (size_t)BB * SS * 4, stream);

  // Q,K projections fused (z=0: enc@Wq+bq -> q; z=1: emo@Wk+bk -> k), 3-term
  // (lo output written only for z==0; k_lo region now holds mask bits)
  mgemm<0, 0, 0, 4><<<dim3(4, 128, 2), blk, 0, stream>>>(
      enc_h, enc_l, wq_h, wq_l, q_hi, q_lo, bq, bk, nullptr, nullptr, nullptr,
      EE, EE, EE, EE, 2 * SZ, (size_t)2 * EE * EE, 2 * SZ, 0);
  // vT[e][b*T+t] = Wv[e,:].emo[b*T+t,:] + bv[e]   (tiled, ldc = B*T)
  mgemm<1, 1, 1, 4><<<dim3(128, 4, 1), blk, 0, stream>>>(
      wv_h, nullptr, emo_h, nullptr, vT, nullptr, bv, nullptr, nullptr,
      nullptr, nullptr, EE, EE, EE, BB * TT, 0, 0, 0, 0);

  // logits 2-term -> masked exp(L-60) bf16 tiled + row sums, all 8 batches
  mgemm<0, 1, 5, 4><<<dim3(16, 16, 8), blk, 0, stream>>>(
      q_hi, q_lo, k_hi, nullptr, P_u, nullptr, nullptr, nullptr, nullptr,
      (const int*)mbits, sZ, EE, EE, EE, TT,
      (size_t)SS * EE, (size_t)TT * EE, (size_t)SS * TT, 0);

  // ctx = (P_u @ V) / Z, all 8 batches (vT batch-z k-offset = z*T*16 elems)
  mgemm<1, 1, 6, 4><<<dim3(4, 16, 8), blk, 0, stream>>>(
      P_u, nullptr, vT, nullptr, ctx, nullptr, nullptr, nullptr, nullptr,
      nullptr, sZ, TT, TT, BB * TT, EE,
      (size_t)SS * TT, (size_t)TT * 16, (size_t)SS * EE, 0);

  // x = enc + ctx @ Wo^T  (fp32 row-major into d_out)
  mgemm<1, 1, 4, 4><<<dim3(4, 128, 1), blk, 0, stream>>>(
      ctx, nullptr, wo_h, nullptr, out, nullptr, nullptr, nullptr, enc,
      nullptr, nullptr, EE, EE, EE, EE, 0, 0, 0, 0);
  // out = enc + LN(x), in place
  ln_kernel<<<dim3(BB * SS / 4), blk, 0, stream>>>(out, enc, gamma, beta, out);
}

// Round 6
// 541.611 us; speedup vs baseline: 1.0282x; 1.0282x over previous
//
#include <hip/hip_runtime.h>
#include <math.h>
#include <stdint.h>

// AttnEmo: B=8, S=T=2048, E=512. All-MFMA, fixed-shift unnormalized softmax.
// R13 (on R12):
//  - mask-as-a-pass DELETED. Ledger showed R8-R12's dedicated mask stream cost
//    ~74us no matter its structure (4 rewrites pinned at ~95us prepass), while
//    R7's split-only prepass ran ~21us. A standalone streaming pass over the
//    134MB mask can't beat "read it under MFMA": the logits kernel (EPI=5) now
//    loads its own 128x128 raw-mask patch at kernel START (16 coalesced int4
//    per thread), ballot-packs to 256 u64 in a 2KB LDS region, and the
//    epilogue tests bits from LDS. Mask HBM traffic overlaps the QK^T K-loop.
//  - Pack format (= R12's ballot-natural): word G*4+j bit l = int G*256+4l+j
//    (G = 256-int group of the patch, row-major). Epilogue: lrow=row-bm,
//    word = (lrow>>1)*4+(fr&3), bit = (lrow&1)*32 + (wn>>6)*16 + j*4 + (fr>>2).
//  - prepass = enc/emo hi/lo split only (R12's coalesced no-LDS structure).
// Tiled layout: chunk(row,k) at (row>>4)*16*ld + (k>>3)*128 + (row&15)*8+(k&7)
//  -> gld16 staging lane l fetches base+l*16 (1KB contiguous), lands in
//     fragment order, ds_read base+lane*16, zero bank conflicts (R6-proven).

#define BB 8
#define SS 2048
#define TT 2048
#define EE 512

typedef __attribute__((ext_vector_type(8))) short short8;
typedef __attribute__((ext_vector_type(4))) short short4v;
typedef __attribute__((ext_vector_type(4))) float f32x4;

__device__ __forceinline__ uint16_t f2bf(float f) {      // RNE fp32->bf16
  uint32_t u = __builtin_bit_cast(uint32_t, f);
  u += 0x7fffu + ((u >> 16) & 1u);
  return (uint16_t)(u >> 16);
}
__device__ __forceinline__ float bf2f(uint16_t h) {
  uint32_t u = ((uint32_t)h) << 16;
  return __builtin_bit_cast(float, u);
}

// tiled element offset (ld = row length in elements, multiple of 8)
__device__ __forceinline__ size_t toff(int row, int col, int ld) {
  return (size_t)(row >> 4) * ((size_t)ld << 4) + ((size_t)(col >> 3) << 7)
       + ((row & 15) << 3) + (col & 7);
}

// async global->LDS, 16B per lane; LDS dest = wave-uniform base + lane*16
__device__ __forceinline__ void gld16(const void* g, void* l) {
  __builtin_amdgcn_global_load_lds(
      (const __attribute__((address_space(1))) void*)g,
      (__attribute__((address_space(3))) void*)l, 16, 0, 0);
}

// ---------------------------------------------------------------------------
// NT MFMA GEMM: C[m,n] = sum_k A[m,k]*B[n,k]  (both K-major, TILED layout)
// ASRC: 0 = bf16 hi+lo arrays   1 = bf16 hi only
// BSRC: 0 = bf16 hi+lo arrays   1 = bf16 hi only
//   terms: A0/B0 -> 3 (hh, hl, lh);  A0/B1 -> 2 (hh, lh);  A1/B1 -> 1
// EPI:  0 = +biasz[col], split bf16 out tiled (Cp=hi, C2=lo; lo only z==0)
//       1 = +bias[row], bf16 out tiled                        (vT proj)
//       4 = +resid, fp32 out ROW-MAJOR                        (Wo + residual)
//       5 = RAW mask patch prefetch+ballot-pack -> P_u=exp(L-60) bf16 tiled
//           + atomicAdd row-sum into sZ
//       6 = val / sZ[row], bf16 out tiled                     (PV normalize)
// WN: wave n-tiles (4 -> 128-wide block). M-tile = 128. 256 threads.
// ---------------------------------------------------------------------------
template<int ASRC, int BSRC, int EPI, int WN>
__global__ __launch_bounds__(256, 2) void mgemm(
    const void* __restrict__ Ap, const void* __restrict__ Alo,
    const void* __restrict__ Bp, const void* __restrict__ Blo,
    void* __restrict__ Cp, void* __restrict__ C2,
    const float* __restrict__ bias, const float* __restrict__ bias2,
    const float* __restrict__ resid,
    const int* __restrict__ mask, float* __restrict__ sZ,
    int K, int lda, int ldb, int ldc,
    size_t sA, size_t sB, size_t sC, size_t sM)
{
  constexpr bool ALOARR = (ASRC == 0);
  constexpr bool BLOARR = (BSRC == 0);
  constexpr bool T3     = (ASRC == 0) && (BSRC == 0);
  constexpr bool T2     = (ASRC == 0) && (BSRC == 1);
  constexpr int  BN     = 32 * WN;
  constexpr int  ABYTES = ALOARR ? 16384 : 8192;
  constexpr int  BBYTES = BLOARR ? BN * 128 : BN * 64;

  __shared__ char smem[ABYTES + BBYTES];
  __shared__ unsigned long long pm[(EPI == 5) ? 256 : 1];  // packed mask patch

  const int tid  = threadIdx.x;
  const int lane = tid & 63, wv = tid >> 6;
  const int z    = blockIdx.z;
  const int bm   = blockIdx.y * 128;
  const int bn   = blockIdx.x * BN;
  const int fr   = lane & 15;            // fragment row/col
  const int wm   = (wv & 1) * 64;
  const int wn   = (wv >> 1) * (16 * WN);

  // ---- EPI 5: prefetch this block's 128x128 raw-mask patch, pack to LDS ----
  // Loads issue before the K-loop; HBM latency overlaps the first K-steps.
  // Coalescing: half-wave (32 lanes) reads 512B contiguous (one mask row seg).
  // Wave w, round r covers patch rows r*8+2w, r*8+2w+1 = 256 consecutive ints
  // = group G = r*4+w; ballot of component j = word G*4+j (bit l = int 4l+j).
  if constexpr (EPI == 5) {
    const int* mz = mask + sM * z;
    int4 mm[16];
#pragma unroll
    for (int r = 0; r < 16; ++r)
      mm[r] = *(const int4*)(mz + (size_t)(bm + r * 8 + (tid >> 5)) * ldc
                                + bn + (tid & 31) * 4);
#pragma unroll
    for (int r = 0; r < 16; ++r) {
      const unsigned long long b0 = __ballot(mm[r].x != 0);
      const unsigned long long b1 = __ballot(mm[r].y != 0);
      const unsigned long long b2 = __ballot(mm[r].z != 0);
      const unsigned long long b3 = __ballot(mm[r].w != 0);
      if (lane < 4) {
        const unsigned long long w64 = (lane == 0) ? b0 : (lane == 1) ? b1
                                     : (lane == 2) ? b2 : b3;
        pm[(r * 4 + wv) * 4 + lane] = w64;
      }
    }
    // visibility: first __syncthreads() of the K-loop covers these writes
  }

  const f32x4 zero = {0.f, 0.f, 0.f, 0.f};
  f32x4 acc[4][WN];
#pragma unroll
  for (int i = 0; i < 4; ++i)
#pragma unroll
    for (int j = 0; j < WN; ++j) acc[i][j] = zero;

  // tiled layout: staging lane l's offset within a (16-row x 32-k) seg-tile
  // is just l*8 elements (l*16 bytes) -- fully contiguous per gld16.
  const size_t loff = (size_t)lane * 8;
  const uint16_t* gAh = (const uint16_t*)Ap + sA * z + (size_t)(bm >> 4) * 16 * lda + loff;
  const uint16_t* gAl = ALOARR ? (const uint16_t*)Alo + sA * z + (size_t)(bm >> 4) * 16 * lda + loff : nullptr;
  const uint16_t* gBh = (const uint16_t*)Bp + sB * z + (size_t)(bn >> 4) * 16 * ldb + loff;
  const uint16_t* gBl = BLOARR ? (const uint16_t*)Blo + sB * z + (size_t)(bn >> 4) * 16 * ldb + loff : nullptr;

  for (int k0 = 0; k0 < K; k0 += 32) {
    const size_t ka = (size_t)k0 * 16;           // (k0>>3)*128 elements
    __syncthreads();                       // previous tiles fully consumed
    // ---- stage A (8 segs x 1KB each) ----
#pragma unroll
    for (int t = 0; t < 2; ++t) { int s = wv + t * 4;
      gld16(gAh + (size_t)s * 16 * lda + ka, &smem[s * 1024]); }
    if constexpr (ALOARR) {
#pragma unroll
      for (int t = 0; t < 2; ++t) { int s = wv + t * 4;
        gld16(gAl + (size_t)s * 16 * lda + ka, &smem[8192 + s * 1024]); }
    }
    // ---- stage B ----
#pragma unroll
    for (int t = 0; t < WN / 2; ++t) { int s = wv + t * 4;
      gld16(gBh + (size_t)s * 16 * ldb + ka, &smem[ABYTES + s * 1024]); }
    if constexpr (BLOARR) {
#pragma unroll
      for (int t = 0; t < WN / 2; ++t) { int s = wv + t * 4;
        gld16(gBl + (size_t)s * 16 * ldb + ka, &smem[ABYTES + BN * 64 + s * 1024]); }
    }
    __syncthreads();                       // staging landed

    // ---- fragments: each wave reads base + lane*16 (conflict-free) ----
    short8 ah[4], bh[WN], al_[4], bl_[WN];
#pragma unroll
    for (int i = 0; i < 4; ++i) {
      const char* p = smem + ((wm >> 4) + i) * 1024 + (lane << 4);
      ah[i] = *(const short8*)p;
      if constexpr (ALOARR) al_[i] = *(const short8*)(p + 8192);
    }
#pragma unroll
    for (int j = 0; j < WN; ++j) {
      const char* p = smem + ABYTES + ((wn >> 4) + j) * 1024 + (lane << 4);
      bh[j] = *(const short8*)p;
      if constexpr (BLOARR) bl_[j] = *(const short8*)(p + BN * 64);
    }
    // ---- MFMA ----
#pragma unroll
    for (int i = 0; i < 4; ++i)
#pragma unroll
      for (int j = 0; j < WN; ++j) {
        acc[i][j] = __builtin_amdgcn_mfma_f32_16x16x32_bf16(ah[i], bh[j], acc[i][j], 0, 0, 0);
        if constexpr (T3) {
          acc[i][j] = __builtin_amdgcn_mfma_f32_16x16x32_bf16(ah[i], bl_[j], acc[i][j], 0, 0, 0);
          acc[i][j] = __builtin_amdgcn_mfma_f32_16x16x32_bf16(al_[i], bh[j], acc[i][j], 0, 0, 0);
        } else if constexpr (T2) {
          acc[i][j] = __builtin_amdgcn_mfma_f32_16x16x32_bf16(al_[i], bh[j], acc[i][j], 0, 0, 0);
        }
      }
  }

  // ---- epilogue: C/D layout col=lane&15, row=(lane>>4)*4+reg ----
  if constexpr (EPI == 5) {
    // bit test from LDS-packed patch:
    //   lrow = row-bm, word = (lrow>>1)*4 + (fr&3),
    //   bit  = (lrow&1)*32 + (wn>>6)*16 + j*4 + (fr>>2)
    const int sh0 = (wn >> 6) * 16 + (fr >> 2);
    unsigned long long mw[4][4];
#pragma unroll
    for (int i = 0; i < 4; ++i)
#pragma unroll
      for (int g = 0; g < 4; ++g) {
        const int lrow = wm + i * 16 + (lane >> 4) * 4 + g;
        mw[i][g] = pm[(lrow >> 1) * 4 + (fr & 3)];
      }
#pragma unroll
    for (int i = 0; i < 4; ++i) {
      const int row0 = bm + wm + i * 16 + (lane >> 4) * 4;
#pragma unroll
      for (int g = 0; g < 4; ++g) {
        const int row = row0 + g;
        const int sh  = sh0 + (g & 1) * 32;      // lrow parity == g parity
        float rs = 0.f;
#pragma unroll
        for (int j = 0; j < WN; ++j) {
          const int col = bn + wn + j * 16 + fr;
          const bool msk = (mw[i][g] >> (sh + j * 4)) & 1ull;
          const float e = msk ? 0.f : __expf(acc[i][j][g] - 60.0f);
          ((uint16_t*)Cp)[sC * z + toff(row, col, ldc)] = f2bf(e);
          rs += e;
        }
        rs += __shfl_xor(rs, 1);
        rs += __shfl_xor(rs, 2);
        rs += __shfl_xor(rs, 4);
        rs += __shfl_xor(rs, 8);
        if ((lane & 15) == 0) atomicAdd(&sZ[(size_t)z * SS + row], rs);
      }
    }
  } else {
#pragma unroll
    for (int i = 0; i < 4; ++i) {
      const int row0 = bm + wm + i * 16 + (lane >> 4) * 4;
#pragma unroll
      for (int g = 0; g < 4; ++g) {
        const int row = row0 + g;
        float invZ = 1.0f;
        if constexpr (EPI == 6) invZ = 1.0f / sZ[(size_t)z * SS + row];
#pragma unroll
        for (int j = 0; j < WN; ++j) {
          const int col = bn + wn + j * 16 + fr;
          float v = acc[i][j][g];
          if constexpr (EPI == 0) {
            const float* bp = (z == 0) ? bias : bias2;
            const size_t ci = sC * z + toff(row, col, ldc);
            v += bp[col];
            uint16_t h = f2bf(v);
            ((uint16_t*)Cp)[ci] = h;
            // lo term only consumed for q (z==0) -- skip dead k_lo writes
            if (z == 0) ((uint16_t*)C2)[ci] = f2bf(v - bf2f(h));
          } else if constexpr (EPI == 1) {
            v += bias[row];
            ((uint16_t*)Cp)[sC * z + toff(row, col, ldc)] = f2bf(v);
          } else if constexpr (EPI == 4) {
            v += resid[(size_t)row * ldc + col];
            ((float*)Cp)[sC * z + (size_t)row * ldc + col] = v;
          } else {  // EPI == 6
            ((uint16_t*)Cp)[sC * z + toff(row, col, ldc)] = f2bf(v * invZ);
          }
        }
      }
    }
  }
}

// ---------------- fp32 [Rx512] row-major -> hi/lo bf16 TILED ---------------
// Core: one block = 16 rows x 128 cols = 2048 elements. (weights only)
__device__ __forceinline__ void split_core(
    const float* __restrict__ x, uint16_t* __restrict__ hi,
    uint16_t* __restrict__ lo, int bid)
{
  __shared__ uint16_t lh[256 * 8 + 16 * 8];   // 16B chunks, 16B pad per 16
  __shared__ uint16_t ll[256 * 8 + 16 * 8];
  const int t   = threadIdx.x;
  const int seg = bid >> 2, q = bid & 3;

  const float* src = x + (size_t)(seg * 16 + (t >> 4)) * 512 + q * 128 + (t & 15) * 8;
  float4 a = *(const float4*)src;
  float4 b = *(const float4*)(src + 4);
  float v[8] = {a.x, a.y, a.z, a.w, b.x, b.y, b.z, b.w};

  const int slot = (t & 15) * 16 + (t >> 4);
  uint16_t* ph = lh + slot * 8 + (slot >> 4) * 8;
  uint16_t* pl = ll + slot * 8 + (slot >> 4) * 8;
#pragma unroll
  for (int e = 0; e < 8; ++e) {
    uint16_t h = f2bf(v[e]);
    ph[e] = h;
    pl[e] = f2bf(v[e] - bf2f(h));
  }
  __syncthreads();

  const uint16_t* qh = lh + t * 8 + (t >> 4) * 8;
  const uint16_t* ql = ll + t * 8 + (t >> 4) * 8;
  const size_t off = (size_t)seg * 8192 + (size_t)(q * 16 + (t >> 4)) * 128 + (t & 15) * 8;
  *(short8*)(hi + off) = *(const short8*)qh;
  *(short8*)(lo + off) = *(const short8*)ql;
}

// ---------------- coalesced streaming prepass: enc/emo split only ----------
// Grid: exactly 2048 blocks x 256 threads. No LDS, no barriers.
// blocks 0-1023: enc; 1024-2047: emo. 2048*256*8 float4 = enc+emo exactly.
__global__ __launch_bounds__(256) void prepass(
    const float* __restrict__ enc, const float* __restrict__ emo,
    uint16_t* __restrict__ hi, uint16_t* __restrict__ lo, size_t stride)
{
  const int t    = threadIdx.x;
  const int arr  = blockIdx.x >> 10;              // 0: enc, 1: emo
  const int lb   = blockIdx.x & 1023;             // local block within array

  const float* src = (arr ? emo : enc);
  float4 f[8];
#pragma unroll
  for (int r = 0; r < 8; ++r)
    f[r] = *((const float4*)src + (size_t)lb * 2048 + r * 256 + t);

  // split: each float4 = 4 consecutive k of one row -> short4 hi/lo stores
  uint16_t* hp = hi + (size_t)arr * stride;
  uint16_t* lp = lo + (size_t)arr * stride;
#pragma unroll
  for (int r = 0; r < 8; ++r) {
    const int lf  = lb * 2048 + r * 256 + t;      // float4 index within array
    const int row = lf >> 7;                      // 128 float4 per 512-row
    const int k   = (lf & 127) * 4;
    const size_t off = (size_t)(row >> 4) * 8192 + (size_t)(k >> 3) * 128
                     + (row & 15) * 8 + (k & 7);
    const float v[4] = {f[r].x, f[r].y, f[r].z, f[r].w};
    short4v hv, lv;
#pragma unroll
    for (int e = 0; e < 4; ++e) {
      const uint16_t h = f2bf(v[e]);
      hv[e] = (short)h;
      lv[e] = (short)f2bf(v[e] - bf2f(h));
    }
    *(short4v*)(hp + off) = hv;
    *(short4v*)(lp + off) = lv;
  }
}

// 4 weight matrices in one launch: grid 512 (128 each); hi/lo bufs contiguous
__global__ __launch_bounds__(256) void split_w4(
    const float* __restrict__ x0, const float* __restrict__ x1,
    const float* __restrict__ x2, const float* __restrict__ x3,
    uint16_t* __restrict__ hi0, uint16_t* __restrict__ lo0, size_t stride)
{
  const int w   = blockIdx.x >> 7;
  const int bid = blockIdx.x & 127;
  const float* x = (w == 0) ? x0 : (w == 1) ? x1 : (w == 2) ? x2 : x3;
  split_core(x, hi0 + w * stride, lo0 + w * stride, bid);
}

// ---------------- fused LayerNorm epilogue (in-place safe) -----------------
__global__ __launch_bounds__(256) void ln_kernel(
    const float* __restrict__ X, const float* __restrict__ enc,
    const float* __restrict__ gamma, const float* __restrict__ beta,
    float* __restrict__ out)
{
  const int row = blockIdx.x * 4 + (threadIdx.x >> 6);
  const int lane = threadIdx.x & 63;
  const size_t base = (size_t)row * EE;
  const int o0 = lane * 4, o1 = 256 + lane * 4;

  float4 x0 = *(const float4*)(X + base + o0);
  float4 x1 = *(const float4*)(X + base + o1);
  float s = x0.x + x0.y + x0.z + x0.w + x1.x + x1.y + x1.z + x1.w;
#pragma unroll
  for (int off = 32; off > 0; off >>= 1) s += __shfl_xor(s, off);
  const float mean = s * (1.0f / 512.0f);

  float d[8] = {x0.x - mean, x0.y - mean, x0.z - mean, x0.w - mean,
                x1.x - mean, x1.y - mean, x1.z - mean, x1.w - mean};
  float s2 = 0.f;
#pragma unroll
  for (int i = 0; i < 8; ++i) s2 = fmaf(d[i], d[i], s2);
#pragma unroll
  for (int off = 32; off > 0; off >>= 1) s2 += __shfl_xor(s2, off);
  const float stdv = sqrtf(s2 * (1.0f / 512.0f));
  const float inv = 1.0f / (stdv + 1e-6f);

  float4 g0 = *(const float4*)(gamma + o0);
  float4 g1 = *(const float4*)(gamma + o1);
  float4 b0 = *(const float4*)(beta + o0);
  float4 b1 = *(const float4*)(beta + o1);
  float4 e0 = *(const float4*)(enc + base + o0);
  float4 e1 = *(const float4*)(enc + base + o1);

  float4 r0, r1;
  r0.x = e0.x + g0.x * d[0] * inv + b0.x;
  r0.y = e0.y + g0.y * d[1] * inv + b0.y;
  r0.z = e0.z + g0.z * d[2] * inv + b0.z;
  r0.w = e0.w + g0.w * d[3] * inv + b0.w;
  r1.x = e1.x + g1.x * d[4] * inv + b1.x;
  r1.y = e1.y + g1.y * d[5] * inv + b1.y;
  r1.z = e1.z + g1.z * d[6] * inv + b1.z;
  r1.w = e1.w + g1.w * d[7] * inv + b1.w;
  *(float4*)(out + base + o0) = r0;
  *(float4*)(out + base + o1) = r1;
}

extern "C" void kernel_launch(void* const* d_in, const int* in_sizes, int n_in,
                              void* d_out, int out_size, void* d_ws, size_t ws_size,
                              hipStream_t stream) {
  const float* enc   = (const float*)d_in[0];
  const float* emo   = (const float*)d_in[1];
  const int*   mask  = (const int*)d_in[2];
  const float* Wq    = (const float*)d_in[3];
  const float* bq    = (const float*)d_in[4];
  const float* Wk    = (const float*)d_in[5];
  const float* bk    = (const float*)d_in[6];
  const float* Wv    = (const float*)d_in[7];
  const float* bv    = (const float*)d_in[8];
  const float* Wo    = (const float*)d_in[9];
  const float* gamma = (const float*)d_in[10];
  const float* beta  = (const float*)d_in[11];
  float* out = (float*)d_out;
  char*  ws  = (char*)d_ws;

  const size_t SZ = (size_t)BB * SS * EE;   // 8,388,608
  size_t off = 0;
  // adjacency matters: (enc_h,enc_l,emo_h,emo_l) stride 2SZ for fused QK A;
  // (q_hi,q_lo,k_hi,k_lo) stride 2SZ for fused QK C;
  // (wq_h,wq_l,wk_h,wk_l,...) stride 2*EE*EE for fused QK B and split_w4.
  uint16_t* enc_h = (uint16_t*)(ws + off); off += SZ * 2;
  uint16_t* enc_l = (uint16_t*)(ws + off); off += SZ * 2;
  uint16_t* emo_h = (uint16_t*)(ws + off); off += SZ * 2;
  uint16_t* emo_l = (uint16_t*)(ws + off); off += SZ * 2;
  uint16_t* q_hi  = (uint16_t*)(ws + off); off += SZ * 2;
  uint16_t* q_lo  = (uint16_t*)(ws + off); off += SZ * 2;
  uint16_t* k_hi  = (uint16_t*)(ws + off); off += SZ * 2;
  uint16_t* k_lo  = (uint16_t*)(ws + off); off += SZ * 2;  // dead (never read)
  uint16_t* vT    = (uint16_t*)(ws + off); off += SZ * 2;   // [E][B*T] tiled
  uint16_t* ctx   = (uint16_t*)(ws + off); off += SZ * 2;   // [B*S][E] tiled
  uint16_t* wq_h  = (uint16_t*)(ws + off); off += EE * EE * 2;
  uint16_t* wq_l  = (uint16_t*)(ws + off); off += EE * EE * 2;
  uint16_t* wk_h  = (uint16_t*)(ws + off); off += EE * EE * 2;
  uint16_t* wk_l  = (uint16_t*)(ws + off); off += EE * EE * 2;
  uint16_t* wv_h  = (uint16_t*)(ws + off); off += EE * EE * 2;
  uint16_t* wv_l  = (uint16_t*)(ws + off); off += EE * EE * 2;
  uint16_t* wo_h  = (uint16_t*)(ws + off); off += EE * EE * 2;
  uint16_t* wo_l  = (uint16_t*)(ws + off); off += EE * EE * 2;
  uint16_t* P_u   = (uint16_t*)(ws + off); off += (size_t)BB * SS * TT * 2;  // 67MB
  float*    sZ    = (float*)(ws + off);    off += (size_t)BB * SS * 4;
  (void)k_lo; (void)wk_l; (void)wv_l; (void)wo_l;

  const dim3 blk(256);

  // weights split + coalesced streaming prepass (enc/emo split only)
  split_w4<<<dim3(512), blk, 0, stream>>>(Wq, Wk, Wv, Wo, wq_h, wq_l,
                                          (size_t)2 * EE * EE);
  prepass<<<dim3(2048), blk, 0, stream>>>(enc, emo, enc_h, enc_l,
                                          (size_t)2 * SZ);
  hipMemsetAsync(sZ, 0, (size_t)BB * SS * 4, stream);

  // Q,K projections fused (z=0: enc@Wq+bq -> q; z=1: emo@Wk+bk -> k), 3-term
  mgemm<0, 0, 0, 4><<<dim3(4, 128, 2), blk, 0, stream>>>(
      enc_h, enc_l, wq_h, wq_l, q_hi, q_lo, bq, bk, nullptr, nullptr, nullptr,
      EE, EE, EE, EE, 2 * SZ, (size_t)2 * EE * EE, 2 * SZ, 0);
  // vT[e][b*T+t] = Wv[e,:].emo[b*T+t,:] + bv[e]   (tiled, ldc = B*T)
  mgemm<1, 1, 1, 4><<<dim3(128, 4, 1), blk, 0, stream>>>(
      wv_h, nullptr, emo_h, nullptr, vT, nullptr, bv, nullptr, nullptr,
      nullptr, nullptr, EE, EE, EE, BB * TT, 0, 0, 0, 0);

  // logits 2-term -> masked exp(L-60) bf16 tiled + row sums, all 8 batches
  // (raw mask read inside the kernel, prefetched+packed under the K-loop)
  mgemm<0, 1, 5, 4><<<dim3(16, 16, 8), blk, 0, stream>>>(
      q_hi, q_lo, k_hi, nullptr, P_u, nullptr, nullptr, nullptr, nullptr,
      mask, sZ, EE, EE, EE, TT,
      (size_t)SS * EE, (size_t)TT * EE, (size_t)SS * TT, (size_t)SS * TT);

  // ctx = (P_u @ V) / Z, all 8 batches (vT batch-z k-offset = z*T*16 elems)
  mgemm<1, 1, 6, 4><<<dim3(4, 16, 8), blk, 0, stream>>>(
      P_u, nullptr, vT, nullptr, ctx, nullptr, nullptr, nullptr, nullptr,
      nullptr, sZ, TT, TT, BB * TT, EE,
      (size_t)SS * TT, (size_t)TT * 16, (size_t)SS * EE, 0);

  // x = enc + ctx @ Wo^T  (fp32 row-major into d_out)
  mgemm<1, 1, 4, 4><<<dim3(4, 128, 1), blk, 0, stream>>>(
      ctx, nullptr, wo_h, nullptr, out, nullptr, nullptr, nullptr, enc,
      nullptr, nullptr, EE, EE, EE, EE, 0, 0, 0, 0);
  // out = enc + LN(x), in place
  ln_kernel<<<dim3(BB * SS / 4), blk, 0, stream>>>(out, enc, gamma, beta, out);
}

// Round 7
// 534.973 us; speedup vs baseline: 1.0410x; 1.0124x over previous
//
#include <hip/hip_runtime.h>
#include <math.h>
#include <stdint.h>

// AttnEmo: B=8, S=T=2048, E=512. All-MFMA, fixed-shift unnormalized softmax.
// R14 (on R13):
//  - prepass reverted to R7's LDS-shuffled split_pair (ledger: 21us vs R13's
//    coalesced-read/scattered-8B-write version at ~42us).
//  - logits mask load PIPELINED: 1 int4/thread/K-iteration (16 iters = full
//    128x128 patch) issued alongside the staging gld16s; the iteration's own
//    vmcnt(0)+barrier lands it; ballots+LDS pack ride after the barrier.
//    R13's 16-load prologue serialized (VGPR=60 -> ~4 in flight) and stalled
//    each block before its K-loop; this hides the mask fetch under MFMA.
//  - pack format & epilogue extraction identical to R13 (passed): word
//    (r*4+wv)*4+j, bit l = int 4l+j of the 256-int group; epilogue word =
//    (lrow>>1)*4+(fr&3), bit = (lrow&1)*32 + (wn>>6)*16 + j*4 + (fr>>2).
// Tiled layout: chunk(row,k) at (row>>4)*16*ld + (k>>3)*128 + (row&15)*8+(k&7)
//  -> gld16 staging lane l fetches base+l*16 (1KB contiguous), lands in
//     fragment order, ds_read base+lane*16, zero bank conflicts (R6-proven).

#define BB 8
#define SS 2048
#define TT 2048
#define EE 512

typedef __attribute__((ext_vector_type(8))) short short8;
typedef __attribute__((ext_vector_type(4))) float f32x4;

__device__ __forceinline__ uint16_t f2bf(float f) {      // RNE fp32->bf16
  uint32_t u = __builtin_bit_cast(uint32_t, f);
  u += 0x7fffu + ((u >> 16) & 1u);
  return (uint16_t)(u >> 16);
}
__device__ __forceinline__ float bf2f(uint16_t h) {
  uint32_t u = ((uint32_t)h) << 16;
  return __builtin_bit_cast(float, u);
}

// tiled element offset (ld = row length in elements, multiple of 8)
__device__ __forceinline__ size_t toff(int row, int col, int ld) {
  return (size_t)(row >> 4) * ((size_t)ld << 4) + ((size_t)(col >> 3) << 7)
       + ((row & 15) << 3) + (col & 7);
}

// async global->LDS, 16B per lane; LDS dest = wave-uniform base + lane*16
__device__ __forceinline__ void gld16(const void* g, void* l) {
  __builtin_amdgcn_global_load_lds(
      (const __attribute__((address_space(1))) void*)g,
      (__attribute__((address_space(3))) void*)l, 16, 0, 0);
}

// ---------------------------------------------------------------------------
// NT MFMA GEMM: C[m,n] = sum_k A[m,k]*B[n,k]  (both K-major, TILED layout)
// ASRC: 0 = bf16 hi+lo arrays   1 = bf16 hi only
// BSRC: 0 = bf16 hi+lo arrays   1 = bf16 hi only
//   terms: A0/B0 -> 3 (hh, hl, lh);  A0/B1 -> 2 (hh, lh);  A1/B1 -> 1
// EPI:  0 = +biasz[col], split bf16 out tiled (Cp=hi, C2=lo; lo only z==0)
//       1 = +bias[row], bf16 out tiled                        (vT proj)
//       4 = +resid, fp32 out ROW-MAJOR                        (Wo + residual)
//       5 = raw mask pipelined under K-loop -> P_u=exp(L-60) bf16 tiled
//           + atomicAdd row-sum into sZ
//       6 = val / sZ[row], bf16 out tiled                     (PV normalize)
// WN: wave n-tiles (4 -> 128-wide block). M-tile = 128. 256 threads.
// ---------------------------------------------------------------------------
template<int ASRC, int BSRC, int EPI, int WN>
__global__ __launch_bounds__(256, 2) void mgemm(
    const void* __restrict__ Ap, const void* __restrict__ Alo,
    const void* __restrict__ Bp, const void* __restrict__ Blo,
    void* __restrict__ Cp, void* __restrict__ C2,
    const float* __restrict__ bias, const float* __restrict__ bias2,
    const float* __restrict__ resid,
    const int* __restrict__ mask, float* __restrict__ sZ,
    int K, int lda, int ldb, int ldc,
    size_t sA, size_t sB, size_t sC, size_t sM)
{
  constexpr bool ALOARR = (ASRC == 0);
  constexpr bool BLOARR = (BSRC == 0);
  constexpr bool T3     = (ASRC == 0) && (BSRC == 0);
  constexpr bool T2     = (ASRC == 0) && (BSRC == 1);
  constexpr int  BN     = 32 * WN;
  constexpr int  ABYTES = ALOARR ? 16384 : 8192;
  constexpr int  BBYTES = BLOARR ? BN * 128 : BN * 64;

  __shared__ char smem[ABYTES + BBYTES];
  __shared__ unsigned long long pm[(EPI == 5) ? 256 : 1];  // packed mask patch

  const int tid  = threadIdx.x;
  const int lane = tid & 63, wv = tid >> 6;
  const int z    = blockIdx.z;
  const int bm   = blockIdx.y * 128;
  const int bn   = blockIdx.x * BN;
  const int fr   = lane & 15;            // fragment row/col
  const int wm   = (wv & 1) * 64;
  const int wn   = (wv >> 1) * (16 * WN);

  const f32x4 zero = {0.f, 0.f, 0.f, 0.f};
  f32x4 acc[4][WN];
#pragma unroll
  for (int i = 0; i < 4; ++i)
#pragma unroll
    for (int j = 0; j < WN; ++j) acc[i][j] = zero;

  // tiled layout: staging lane l's offset within a (16-row x 32-k) seg-tile
  // is just l*8 elements (l*16 bytes) -- fully contiguous per gld16.
  const size_t loff = (size_t)lane * 8;
  const uint16_t* gAh = (const uint16_t*)Ap + sA * z + (size_t)(bm >> 4) * 16 * lda + loff;
  const uint16_t* gAl = ALOARR ? (const uint16_t*)Alo + sA * z + (size_t)(bm >> 4) * 16 * lda + loff : nullptr;
  const uint16_t* gBh = (const uint16_t*)Bp + sB * z + (size_t)(bn >> 4) * 16 * ldb + loff;
  const uint16_t* gBl = BLOARR ? (const uint16_t*)Blo + sB * z + (size_t)(bn >> 4) * 16 * ldb + loff : nullptr;

  for (int k0 = 0; k0 < K; k0 += 32) {
    const size_t ka = (size_t)k0 * 16;           // (k0>>3)*128 elements
    const int r = k0 >> 5;                       // K-iteration index
    __syncthreads();                       // previous tiles fully consumed
    // ---- stage A (8 segs x 1KB each) ----
#pragma unroll
    for (int t = 0; t < 2; ++t) { int s = wv + t * 4;
      gld16(gAh + (size_t)s * 16 * lda + ka, &smem[s * 1024]); }
    if constexpr (ALOARR) {
#pragma unroll
      for (int t = 0; t < 2; ++t) { int s = wv + t * 4;
        gld16(gAl + (size_t)s * 16 * lda + ka, &smem[8192 + s * 1024]); }
    }
    // ---- stage B ----
#pragma unroll
    for (int t = 0; t < WN / 2; ++t) { int s = wv + t * 4;
      gld16(gBh + (size_t)s * 16 * ldb + ka, &smem[ABYTES + s * 1024]); }
    if constexpr (BLOARR) {
#pragma unroll
      for (int t = 0; t < WN / 2; ++t) { int s = wv + t * 4;
        gld16(gBl + (size_t)s * 16 * ldb + ka, &smem[ABYTES + BN * 64 + s * 1024]); }
    }
    // ---- EPI 5: one mask int4/thread/iteration rides with the staging ----
    // 16 iterations cover the 128x128 patch (rows r*8 + tid>>5).
    int4 mm;
    if constexpr (EPI == 5)
      mm = *(const int4*)(mask + sM * z + (size_t)(bm + r * 8 + (tid >> 5)) * ldc
                               + bn + (tid & 31) * 4);
    __syncthreads();                       // staging (and mm) landed

    if constexpr (EPI == 5) {
      // ballot-pack this round: group G = r*4+wv (256 consecutive ints);
      // word G*4+j bit l = (int 4l+j != 0).
      const unsigned long long b0 = __ballot(mm.x != 0);
      const unsigned long long b1 = __ballot(mm.y != 0);
      const unsigned long long b2 = __ballot(mm.z != 0);
      const unsigned long long b3 = __ballot(mm.w != 0);
      if (lane < 4) {
        const unsigned long long w64 = (lane == 0) ? b0 : (lane == 1) ? b1
                                     : (lane == 2) ? b2 : b3;
        pm[(r * 4 + wv) * 4 + lane] = w64;
      }
    }

    // ---- fragments: each wave reads base + lane*16 (conflict-free) ----
    short8 ah[4], bh[WN], al_[4], bl_[WN];
#pragma unroll
    for (int i = 0; i < 4; ++i) {
      const char* p = smem + ((wm >> 4) + i) * 1024 + (lane << 4);
      ah[i] = *(const short8*)p;
      if constexpr (ALOARR) al_[i] = *(const short8*)(p + 8192);
    }
#pragma unroll
    for (int j = 0; j < WN; ++j) {
      const char* p = smem + ABYTES + ((wn >> 4) + j) * 1024 + (lane << 4);
      bh[j] = *(const short8*)p;
      if constexpr (BLOARR) bl_[j] = *(const short8*)(p + BN * 64);
    }
    // ---- MFMA ----
#pragma unroll
    for (int i = 0; i < 4; ++i)
#pragma unroll
      for (int j = 0; j < WN; ++j) {
        acc[i][j] = __builtin_amdgcn_mfma_f32_16x16x32_bf16(ah[i], bh[j], acc[i][j], 0, 0, 0);
        if constexpr (T3) {
          acc[i][j] = __builtin_amdgcn_mfma_f32_16x16x32_bf16(ah[i], bl_[j], acc[i][j], 0, 0, 0);
          acc[i][j] = __builtin_amdgcn_mfma_f32_16x16x32_bf16(al_[i], bh[j], acc[i][j], 0, 0, 0);
        } else if constexpr (T2) {
          acc[i][j] = __builtin_amdgcn_mfma_f32_16x16x32_bf16(al_[i], bh[j], acc[i][j], 0, 0, 0);
        }
      }
  }

  // ---- epilogue: C/D layout col=lane&15, row=(lane>>4)*4+reg ----
  if constexpr (EPI == 5) {
    __syncthreads();                       // pm writes visible across waves
    // bit test from LDS-packed patch:
    //   lrow = row-bm, word = (lrow>>1)*4 + (fr&3),
    //   bit  = (lrow&1)*32 + (wn>>6)*16 + j*4 + (fr>>2)
    const int sh0 = (wn >> 6) * 16 + (fr >> 2);
    unsigned long long mw[4][4];
#pragma unroll
    for (int i = 0; i < 4; ++i)
#pragma unroll
      for (int g = 0; g < 4; ++g) {
        const int lrow = wm + i * 16 + (lane >> 4) * 4 + g;
        mw[i][g] = pm[(lrow >> 1) * 4 + (fr & 3)];
      }
#pragma unroll
    for (int i = 0; i < 4; ++i) {
      const int row0 = bm + wm + i * 16 + (lane >> 4) * 4;
#pragma unroll
      for (int g = 0; g < 4; ++g) {
        const int row = row0 + g;
        const int sh  = sh0 + (g & 1) * 32;      // lrow parity == g parity
        float rs = 0.f;
#pragma unroll
        for (int j = 0; j < WN; ++j) {
          const int col = bn + wn + j * 16 + fr;
          const bool msk = (mw[i][g] >> (sh + j * 4)) & 1ull;
          const float e = msk ? 0.f : __expf(acc[i][j][g] - 60.0f);
          ((uint16_t*)Cp)[sC * z + toff(row, col, ldc)] = f2bf(e);
          rs += e;
        }
        rs += __shfl_xor(rs, 1);
        rs += __shfl_xor(rs, 2);
        rs += __shfl_xor(rs, 4);
        rs += __shfl_xor(rs, 8);
        if ((lane & 15) == 0) atomicAdd(&sZ[(size_t)z * SS + row], rs);
      }
    }
  } else {
#pragma unroll
    for (int i = 0; i < 4; ++i) {
      const int row0 = bm + wm + i * 16 + (lane >> 4) * 4;
#pragma unroll
      for (int g = 0; g < 4; ++g) {
        const int row = row0 + g;
        float invZ = 1.0f;
        if constexpr (EPI == 6) invZ = 1.0f / sZ[(size_t)z * SS + row];
#pragma unroll
        for (int j = 0; j < WN; ++j) {
          const int col = bn + wn + j * 16 + fr;
          float v = acc[i][j][g];
          if constexpr (EPI == 0) {
            const float* bp = (z == 0) ? bias : bias2;
            const size_t ci = sC * z + toff(row, col, ldc);
            v += bp[col];
            uint16_t h = f2bf(v);
            ((uint16_t*)Cp)[ci] = h;
            // lo term only consumed for q (z==0) -- skip dead k_lo writes
            if (z == 0) ((uint16_t*)C2)[ci] = f2bf(v - bf2f(h));
          } else if constexpr (EPI == 1) {
            v += bias[row];
            ((uint16_t*)Cp)[sC * z + toff(row, col, ldc)] = f2bf(v);
          } else if constexpr (EPI == 4) {
            v += resid[(size_t)row * ldc + col];
            ((float*)Cp)[sC * z + (size_t)row * ldc + col] = v;
          } else {  // EPI == 6
            ((uint16_t*)Cp)[sC * z + toff(row, col, ldc)] = f2bf(v * invZ);
          }
        }
      }
    }
  }
}

// ---------------- fp32 [Rx512] row-major -> hi/lo bf16 TILED ---------------
// Core: one block = 16 rows x 128 cols = 2048 elements.
// LDS shuffle -> 16B/lane fully-contiguous stores (R7-proven, ~6.4 TB/s).
__device__ __forceinline__ void split_core(
    const float* __restrict__ x, uint16_t* __restrict__ hi,
    uint16_t* __restrict__ lo, int bid)
{
  __shared__ uint16_t lh[256 * 8 + 16 * 8];   // 16B chunks, 16B pad per 16
  __shared__ uint16_t ll[256 * 8 + 16 * 8];
  const int t   = threadIdx.x;
  const int seg = bid >> 2, q = bid & 3;

  const float* src = x + (size_t)(seg * 16 + (t >> 4)) * 512 + q * 128 + (t & 15) * 8;
  float4 a = *(const float4*)src;
  float4 b = *(const float4*)(src + 4);
  float v[8] = {a.x, a.y, a.z, a.w, b.x, b.y, b.z, b.w};

  const int slot = (t & 15) * 16 + (t >> 4);
  uint16_t* ph = lh + slot * 8 + (slot >> 4) * 8;
  uint16_t* pl = ll + slot * 8 + (slot >> 4) * 8;
#pragma unroll
  for (int e = 0; e < 8; ++e) {
    uint16_t h = f2bf(v[e]);
    ph[e] = h;
    pl[e] = f2bf(v[e] - bf2f(h));
  }
  __syncthreads();

  const uint16_t* qh = lh + t * 8 + (t >> 4) * 8;
  const uint16_t* ql = ll + t * 8 + (t >> 4) * 8;
  const size_t off = (size_t)seg * 8192 + (size_t)(q * 16 + (t >> 4)) * 128 + (t & 15) * 8;
  *(short8*)(hi + off) = *(const short8*)qh;
  *(short8*)(lo + off) = *(const short8*)ql;
}

// enc + emo in one launch: grid 8192 (4096 each)  [R7-proven structure]
__global__ __launch_bounds__(256) void split_pair(
    const float* __restrict__ x0, const float* __restrict__ x1,
    uint16_t* __restrict__ hi, uint16_t* __restrict__ lo, size_t stride)
{
  const int sel = blockIdx.x >> 12;            // 0: enc, 1: emo
  const int bid = blockIdx.x & 4095;
  split_core(sel ? x1 : x0, hi + sel * stride, lo + sel * stride, bid);
}

// 4 weight matrices in one launch: grid 512 (128 each); hi/lo bufs contiguous
__global__ __launch_bounds__(256) void split_w4(
    const float* __restrict__ x0, const float* __restrict__ x1,
    const float* __restrict__ x2, const float* __restrict__ x3,
    uint16_t* __restrict__ hi0, uint16_t* __restrict__ lo0, size_t stride)
{
  const int w   = blockIdx.x >> 7;
  const int bid = blockIdx.x & 127;
  const float* x = (w == 0) ? x0 : (w == 1) ? x1 : (w == 2) ? x2 : x3;
  split_core(x, hi0 + w * stride, lo0 + w * stride, bid);
}

// ---------------- fused LayerNorm epilogue (in-place safe) -----------------
__global__ __launch_bounds__(256) void ln_kernel(
    const float* __restrict__ X, const float* __restrict__ enc,
    const float* __restrict__ gamma, const float* __restrict__ beta,
    float* __restrict__ out)
{
  const int row = blockIdx.x * 4 + (threadIdx.x >> 6);
  const int lane = threadIdx.x & 63;
  const size_t base = (size_t)row * EE;
  const int o0 = lane * 4, o1 = 256 + lane * 4;

  float4 x0 = *(const float4*)(X + base + o0);
  float4 x1 = *(const float4*)(X + base + o1);
  float s = x0.x + x0.y + x0.z + x0.w + x1.x + x1.y + x1.z + x1.w;
#pragma unroll
  for (int off = 32; off > 0; off >>= 1) s += __shfl_xor(s, off);
  const float mean = s * (1.0f / 512.0f);

  float d[8] = {x0.x - mean, x0.y - mean, x0.z - mean, x0.w - mean,
                x1.x - mean, x1.y - mean, x1.z - mean, x1.w - mean};
  float s2 = 0.f;
#pragma unroll
  for (int i = 0; i < 8; ++i) s2 = fmaf(d[i], d[i], s2);
#pragma unroll
  for (int off = 32; off > 0; off >>= 1) s2 += __shfl_xor(s2, off);
  const float stdv = sqrtf(s2 * (1.0f / 512.0f));
  const float inv = 1.0f / (stdv + 1e-6f);

  float4 g0 = *(const float4*)(gamma + o0);
  float4 g1 = *(const float4*)(gamma + o1);
  float4 b0 = *(const float4*)(beta + o0);
  float4 b1 = *(const float4*)(beta + o1);
  float4 e0 = *(const float4*)(enc + base + o0);
  float4 e1 = *(const float4*)(enc + base + o1);

  float4 r0, r1;
  r0.x = e0.x + g0.x * d[0] * inv + b0.x;
  r0.y = e0.y + g0.y * d[1] * inv + b0.y;
  r0.z = e0.z + g0.z * d[2] * inv + b0.z;
  r0.w = e0.w + g0.w * d[3] * inv + b0.w;
  r1.x = e1.x + g1.x * d[4] * inv + b1.x;
  r1.y = e1.y + g1.y * d[5] * inv + b1.y;
  r1.z = e1.z + g1.z * d[6] * inv + b1.z;
  r1.w = e1.w + g1.w * d[7] * inv + b1.w;
  *(float4*)(out + base + o0) = r0;
  *(float4*)(out + base + o1) = r1;
}

extern "C" void kernel_launch(void* const* d_in, const int* in_sizes, int n_in,
                              void* d_out, int out_size, void* d_ws, size_t ws_size,
                              hipStream_t stream) {
  const float* enc   = (const float*)d_in[0];
  const float* emo   = (const float*)d_in[1];
  const int*   mask  = (const int*)d_in[2];
  const float* Wq    = (const float*)d_in[3];
  const float* bq    = (const float*)d_in[4];
  const float* Wk    = (const float*)d_in[5];
  const float* bk    = (const float*)d_in[6];
  const float* Wv    = (const float*)d_in[7];
  const float* bv    = (const float*)d_in[8];
  const float* Wo    = (const float*)d_in[9];
  const float* gamma = (const float*)d_in[10];
  const float* beta  = (const float*)d_in[11];
  float* out = (float*)d_out;
  char*  ws  = (char*)d_ws;

  const size_t SZ = (size_t)BB * SS * EE;   // 8,388,608
  size_t off = 0;
  // adjacency matters: (enc_h,enc_l,emo_h,emo_l) stride 2SZ for fused QK A;
  // (q_hi,q_lo,k_hi,k_lo) stride 2SZ for fused QK C;
  // (wq_h,wq_l,wk_h,wk_l,...) stride 2*EE*EE for fused QK B and split_w4.
  uint16_t* enc_h = (uint16_t*)(ws + off); off += SZ * 2;
  uint16_t* enc_l = (uint16_t*)(ws + off); off += SZ * 2;
  uint16_t* emo_h = (uint16_t*)(ws + off); off += SZ * 2;
  uint16_t* emo_l = (uint16_t*)(ws + off); off += SZ * 2;
  uint16_t* q_hi  = (uint16_t*)(ws + off); off += SZ * 2;
  uint16_t* q_lo  = (uint16_t*)(ws + off); off += SZ * 2;
  uint16_t* k_hi  = (uint16_t*)(ws + off); off += SZ * 2;
  uint16_t* k_lo  = (uint16_t*)(ws + off); off += SZ * 2;  // dead (never read)
  uint16_t* vT    = (uint16_t*)(ws + off); off += SZ * 2;   // [E][B*T] tiled
  uint16_t* ctx   = (uint16_t*)(ws + off); off += SZ * 2;   // [B*S][E] tiled
  uint16_t* wq_h  = (uint16_t*)(ws + off); off += EE * EE * 2;
  uint16_t* wq_l  = (uint16_t*)(ws + off); off += EE * EE * 2;
  uint16_t* wk_h  = (uint16_t*)(ws + off); off += EE * EE * 2;
  uint16_t* wk_l  = (uint16_t*)(ws + off); off += EE * EE * 2;
  uint16_t* wv_h  = (uint16_t*)(ws + off); off += EE * EE * 2;
  uint16_t* wv_l  = (uint16_t*)(ws + off); off += EE * EE * 2;
  uint16_t* wo_h  = (uint16_t*)(ws + off); off += EE * EE * 2;
  uint16_t* wo_l  = (uint16_t*)(ws + off); off += EE * EE * 2;
  uint16_t* P_u   = (uint16_t*)(ws + off); off += (size_t)BB * SS * TT * 2;  // 67MB
  float*    sZ    = (float*)(ws + off);    off += (size_t)BB * SS * 4;
  (void)k_lo; (void)wk_l; (void)wv_l; (void)wo_l;

  const dim3 blk(256);

  // weights split + enc/emo split (R7-proven LDS-shuffle structure)
  split_w4<<<dim3(512), blk, 0, stream>>>(Wq, Wk, Wv, Wo, wq_h, wq_l,
                                          (size_t)2 * EE * EE);
  split_pair<<<dim3(8192), blk, 0, stream>>>(enc, emo, enc_h, enc_l,
                                             (size_t)2 * SZ);
  hipMemsetAsync(sZ, 0, (size_t)BB * SS * 4, stream);

  // Q,K projections fused (z=0: enc@Wq+bq -> q; z=1: emo@Wk+bk -> k), 3-term
  mgemm<0, 0, 0, 4><<<dim3(4, 128, 2), blk, 0, stream>>>(
      enc_h, enc_l, wq_h, wq_l, q_hi, q_lo, bq, bk, nullptr, nullptr, nullptr,
      EE, EE, EE, EE, 2 * SZ, (size_t)2 * EE * EE, 2 * SZ, 0);
  // vT[e][b*T+t] = Wv[e,:].emo[b*T+t,:] + bv[e]   (tiled, ldc = B*T)
  mgemm<1, 1, 1, 4><<<dim3(128, 4, 1), blk, 0, stream>>>(
      wv_h, nullptr, emo_h, nullptr, vT, nullptr, bv, nullptr, nullptr,
      nullptr, nullptr, EE, EE, EE, BB * TT, 0, 0, 0, 0);

  // logits 2-term -> masked exp(L-60) bf16 tiled + row sums, all 8 batches
  // (raw mask read inside the kernel, pipelined under the K-loop)
  mgemm<0, 1, 5, 4><<<dim3(16, 16, 8), blk, 0, stream>>>(
      q_hi, q_lo, k_hi, nullptr, P_u, nullptr, nullptr, nullptr, nullptr,
      mask, sZ, EE, EE, EE, TT,
      (size_t)SS * EE, (size_t)TT * EE, (size_t)SS * TT, (size_t)SS * TT);

  // ctx = (P_u @ V) / Z, all 8 batches (vT batch-z k-offset = z*T*16 elems)
  mgemm<1, 1, 6, 4><<<dim3(4, 16, 8), blk, 0, stream>>>(
      P_u, nullptr, vT, nullptr, ctx, nullptr, nullptr, nullptr, nullptr,
      nullptr, sZ, TT, TT, BB * TT, EE,
      (size_t)SS * TT, (size_t)TT * 16, (size_t)SS * EE, 0);

  // x = enc + ctx @ Wo^T  (fp32 row-major into d_out)
  mgemm<1, 1, 4, 4><<<dim3(4, 128, 1), blk, 0, stream>>>(
      ctx, nullptr, wo_h, nullptr, out, nullptr, nullptr, nullptr, enc,
      nullptr, nullptr, EE, EE, EE, EE, 0, 0, 0, 0);
  // out = enc + LN(x), in place
  ln_kernel<<<dim3(BB * SS / 4), blk, 0, stream>>>(out, enc, gamma, beta, out);
}

// Round 8
// 521.096 us; speedup vs baseline: 1.0687x; 1.0266x over previous
//
#include <hip/hip_runtime.h>
#include <math.h>
#include <stdint.h>

// AttnEmo: B=8, S=T=2048, E=512. All-MFMA, fixed-shift unnormalized softmax.
// R15 (on R14):
//  - Mask pack moved INTO the QK-projection GEMM (MPK=1): it has BW slack
//    (fetch ~67MB, 48 MFMA/K-step). 1024 blocks x 16 iters x 2 int4/thread
//    = exactly the 134MB mask; ballots+stores run after each MFMA block, so
//    no MFMA-issue stall (mm landed by the staging barrier anyway).
//  - Logits (EPI=5) reverted to the R12 packed-bits epilogue (HW-validated):
//    reads 4.2MB mbits instead of 134MB raw mask. R13/R14 proved in-kernel
//    raw mask costs ~50us there (dur tracks bytes at ~2.6TB/s effective).
//  - Pack format (R12, proven): word G*4+j bit l = int G*256+4l+j; group
//    Gg = flat_blk*128 + r*8 + wv*2 + p; lane l loads int4 Gg*64+l (1KB/wave
//    contiguous). Epilogue: word = z*65536 + (c0>>8)*4 + (fr&3) + row*32,
//    bit = ((c0&255)>>2) + (fr>>2) + j*4.
//  - prepass: R7 LDS-shuffled split_pair (proven ~21us).
// Tiled layout: chunk(row,k) at (row>>4)*16*ld + (k>>3)*128 + (row&15)*8+(k&7)
//  -> gld16 staging lane l fetches base+l*16 (1KB contiguous), lands in
//     fragment order, ds_read base+lane*16, zero bank conflicts (R6-proven).

#define BB 8
#define SS 2048
#define TT 2048
#define EE 512

typedef __attribute__((ext_vector_type(8))) short short8;
typedef __attribute__((ext_vector_type(4))) float f32x4;

__device__ __forceinline__ uint16_t f2bf(float f) {      // RNE fp32->bf16
  uint32_t u = __builtin_bit_cast(uint32_t, f);
  u += 0x7fffu + ((u >> 16) & 1u);
  return (uint16_t)(u >> 16);
}
__device__ __forceinline__ float bf2f(uint16_t h) {
  uint32_t u = ((uint32_t)h) << 16;
  return __builtin_bit_cast(float, u);
}

// tiled element offset (ld = row length in elements, multiple of 8)
__device__ __forceinline__ size_t toff(int row, int col, int ld) {
  return (size_t)(row >> 4) * ((size_t)ld << 4) + ((size_t)(col >> 3) << 7)
       + ((row & 15) << 3) + (col & 7);
}

// async global->LDS, 16B per lane; LDS dest = wave-uniform base + lane*16
__device__ __forceinline__ void gld16(const void* g, void* l) {
  __builtin_amdgcn_global_load_lds(
      (const __attribute__((address_space(1))) void*)g,
      (__attribute__((address_space(3))) void*)l, 16, 0, 0);
}

// ---------------------------------------------------------------------------
// NT MFMA GEMM: C[m,n] = sum_k A[m,k]*B[n,k]  (both K-major, TILED layout)
// ASRC: 0 = bf16 hi+lo arrays   1 = bf16 hi only
// BSRC: 0 = bf16 hi+lo arrays   1 = bf16 hi only
//   terms: A0/B0 -> 3 (hh, hl, lh);  A0/B1 -> 2 (hh, lh);  A1/B1 -> 1
// EPI:  0 = +biasz[col], split bf16 out tiled (Cp=hi, C2=lo; lo only z==0)
//       1 = +bias[row], bf16 out tiled                        (vT proj)
//       4 = +resid, fp32 out ROW-MAJOR                        (Wo + residual)
//       5 = PACKED mask bits -> P_u=exp(L-60) bf16 tiled + row-sum -> sZ
//       6 = val / sZ[row], bf16 out tiled                     (PV normalize)
// MPK: 1 = also ballot-pack the raw mask into mpk (u64 words) under the
//      K-loop: 2 int4/thread/iter, format = R12 ballot-natural.
// WN: wave n-tiles (4 -> 128-wide block). M-tile = 128. 256 threads.
// ---------------------------------------------------------------------------
template<int ASRC, int BSRC, int EPI, int WN, int MPK>
__global__ __launch_bounds__(256, 2) void mgemm(
    const void* __restrict__ Ap, const void* __restrict__ Alo,
    const void* __restrict__ Bp, const void* __restrict__ Blo,
    void* __restrict__ Cp, void* __restrict__ C2,
    const float* __restrict__ bias, const float* __restrict__ bias2,
    const float* __restrict__ resid,
    const int* __restrict__ mask, float* __restrict__ sZ,
    int K, int lda, int ldb, int ldc,
    size_t sA, size_t sB, size_t sC, size_t sM,
    unsigned long long* __restrict__ mpk)
{
  constexpr bool ALOARR = (ASRC == 0);
  constexpr bool BLOARR = (BSRC == 0);
  constexpr bool T3     = (ASRC == 0) && (BSRC == 0);
  constexpr bool T2     = (ASRC == 0) && (BSRC == 1);
  constexpr int  BN     = 32 * WN;
  constexpr int  ABYTES = ALOARR ? 16384 : 8192;
  constexpr int  BBYTES = BLOARR ? BN * 128 : BN * 64;

  __shared__ char smem[ABYTES + BBYTES];

  const int tid  = threadIdx.x;
  const int lane = tid & 63, wv = tid >> 6;
  const int z    = blockIdx.z;
  const int bm   = blockIdx.y * 128;
  const int bn   = blockIdx.x * BN;
  const int fr   = lane & 15;            // fragment row/col
  const int wm   = (wv & 1) * 64;
  const int wn   = (wv >> 1) * (16 * WN);

  const f32x4 zero = {0.f, 0.f, 0.f, 0.f};
  f32x4 acc[4][WN];
#pragma unroll
  for (int i = 0; i < 4; ++i)
#pragma unroll
    for (int j = 0; j < WN; ++j) acc[i][j] = zero;

  // tiled layout: staging lane l's offset within a (16-row x 32-k) seg-tile
  // is just l*8 elements (l*16 bytes) -- fully contiguous per gld16.
  const size_t loff = (size_t)lane * 8;
  const uint16_t* gAh = (const uint16_t*)Ap + sA * z + (size_t)(bm >> 4) * 16 * lda + loff;
  const uint16_t* gAl = ALOARR ? (const uint16_t*)Alo + sA * z + (size_t)(bm >> 4) * 16 * lda + loff : nullptr;
  const uint16_t* gBh = (const uint16_t*)Bp + sB * z + (size_t)(bn >> 4) * 16 * ldb + loff;
  const uint16_t* gBl = BLOARR ? (const uint16_t*)Blo + sB * z + (size_t)(bn >> 4) * 16 * ldb + loff : nullptr;

  // MPK: flat block id -> this block's 128-group span of the mask
  const int mflat = MPK ? (blockIdx.x + gridDim.x * (blockIdx.y + gridDim.y * blockIdx.z)) : 0;

  for (int k0 = 0; k0 < K; k0 += 32) {
    const size_t ka = (size_t)k0 * 16;           // (k0>>3)*128 elements
    const int r = k0 >> 5;                       // K-iteration index
    __syncthreads();                       // previous tiles fully consumed
    // ---- stage A (8 segs x 1KB each) ----
#pragma unroll
    for (int t = 0; t < 2; ++t) { int s = wv + t * 4;
      gld16(gAh + (size_t)s * 16 * lda + ka, &smem[s * 1024]); }
    if constexpr (ALOARR) {
#pragma unroll
      for (int t = 0; t < 2; ++t) { int s = wv + t * 4;
        gld16(gAl + (size_t)s * 16 * lda + ka, &smem[8192 + s * 1024]); }
    }
    // ---- stage B ----
#pragma unroll
    for (int t = 0; t < WN / 2; ++t) { int s = wv + t * 4;
      gld16(gBh + (size_t)s * 16 * ldb + ka, &smem[ABYTES + s * 1024]); }
    if constexpr (BLOARR) {
#pragma unroll
      for (int t = 0; t < WN / 2; ++t) { int s = wv + t * 4;
        gld16(gBl + (size_t)s * 16 * ldb + ka, &smem[ABYTES + BN * 64 + s * 1024]); }
    }
    // ---- MPK: this iteration's 2 mask int4 ride with the staging ----
    int4 mq0, mq1; int Gg0 = 0;
    if constexpr (MPK) {
      Gg0 = mflat * 128 + r * 8 + wv * 2;        // 2 groups per wave per iter
      mq0 = ((const int4*)mask)[(size_t)Gg0 * 64 + lane];
      mq1 = ((const int4*)mask)[(size_t)(Gg0 + 1) * 64 + lane];
    }
    __syncthreads();                       // staging (and mq) landed

    // ---- fragments: each wave reads base + lane*16 (conflict-free) ----
    short8 ah[4], bh[WN], al_[4], bl_[WN];
#pragma unroll
    for (int i = 0; i < 4; ++i) {
      const char* p = smem + ((wm >> 4) + i) * 1024 + (lane << 4);
      ah[i] = *(const short8*)p;
      if constexpr (ALOARR) al_[i] = *(const short8*)(p + 8192);
    }
#pragma unroll
    for (int j = 0; j < WN; ++j) {
      const char* p = smem + ABYTES + ((wn >> 4) + j) * 1024 + (lane << 4);
      bh[j] = *(const short8*)p;
      if constexpr (BLOARR) bl_[j] = *(const short8*)(p + BN * 64);
    }
    // ---- MFMA ----
#pragma unroll
    for (int i = 0; i < 4; ++i)
#pragma unroll
      for (int j = 0; j < WN; ++j) {
        acc[i][j] = __builtin_amdgcn_mfma_f32_16x16x32_bf16(ah[i], bh[j], acc[i][j], 0, 0, 0);
        if constexpr (T3) {
          acc[i][j] = __builtin_amdgcn_mfma_f32_16x16x32_bf16(ah[i], bl_[j], acc[i][j], 0, 0, 0);
          acc[i][j] = __builtin_amdgcn_mfma_f32_16x16x32_bf16(al_[i], bh[j], acc[i][j], 0, 0, 0);
        } else if constexpr (T2) {
          acc[i][j] = __builtin_amdgcn_mfma_f32_16x16x32_bf16(al_[i], bh[j], acc[i][j], 0, 0, 0);
        }
      }

    // ---- MPK: ballots + store AFTER the MFMAs (no issue stall) ----
    if constexpr (MPK) {
#pragma unroll
      for (int p = 0; p < 2; ++p) {
        const int4 m = p ? mq1 : mq0;
        const unsigned long long b0 = __ballot(m.x != 0);
        const unsigned long long b1 = __ballot(m.y != 0);
        const unsigned long long b2 = __ballot(m.z != 0);
        const unsigned long long b3 = __ballot(m.w != 0);
        if (lane < 4) {
          const unsigned long long w64 = (lane == 0) ? b0 : (lane == 1) ? b1
                                       : (lane == 2) ? b2 : b3;
          mpk[(size_t)(Gg0 + p) * 4 + lane] = w64;
        }
      }
    }
  }

  // ---- epilogue: C/D layout col=lane&15, row=(lane>>4)*4+reg ----
  if constexpr (EPI == 5) {
    // mask = PACKED BITS (R12 format, HW-validated): for 256-int group G,
    // word G*4+j bit l = int G*256+4l+j. For this wave's span c0 = bn+wn:
    //   word = z*65536 + (c0>>8)*4 + (fr&3) + row*32
    //   bit  = ((c0&255)>>2) + (fr>>2) + j*4
    const unsigned long long* __restrict__ mb = (const unsigned long long*)mask;
    const int c0 = bn + wn;
    const int sh = ((c0 & 255) >> 2) + (fr >> 2);
    const size_t mbase = (size_t)z * 65536 + (size_t)((c0 >> 8) << 2) + (fr & 3);
    unsigned long long mw[4][4];
#pragma unroll
    for (int i = 0; i < 4; ++i)
#pragma unroll
      for (int g = 0; g < 4; ++g) {
        const int row = bm + wm + i * 16 + (lane >> 4) * 4 + g;
        mw[i][g] = mb[mbase + (size_t)row * 32];
      }
#pragma unroll
    for (int i = 0; i < 4; ++i) {
      const int row0 = bm + wm + i * 16 + (lane >> 4) * 4;
#pragma unroll
      for (int g = 0; g < 4; ++g) {
        const int row = row0 + g;
        float rs = 0.f;
#pragma unroll
        for (int j = 0; j < WN; ++j) {
          const int col = bn + wn + j * 16 + fr;
          const bool msk = (mw[i][g] >> (sh + j * 4)) & 1ull;
          const float e = msk ? 0.f : __expf(acc[i][j][g] - 60.0f);
          ((uint16_t*)Cp)[sC * z + toff(row, col, ldc)] = f2bf(e);
          rs += e;
        }
        rs += __shfl_xor(rs, 1);
        rs += __shfl_xor(rs, 2);
        rs += __shfl_xor(rs, 4);
        rs += __shfl_xor(rs, 8);
        if ((lane & 15) == 0) atomicAdd(&sZ[(size_t)z * SS + row], rs);
      }
    }
  } else {
#pragma unroll
    for (int i = 0; i < 4; ++i) {
      const int row0 = bm + wm + i * 16 + (lane >> 4) * 4;
#pragma unroll
      for (int g = 0; g < 4; ++g) {
        const int row = row0 + g;
        float invZ = 1.0f;
        if constexpr (EPI == 6) invZ = 1.0f / sZ[(size_t)z * SS + row];
#pragma unroll
        for (int j = 0; j < WN; ++j) {
          const int col = bn + wn + j * 16 + fr;
          float v = acc[i][j][g];
          if constexpr (EPI == 0) {
            const float* bp = (z == 0) ? bias : bias2;
            const size_t ci = sC * z + toff(row, col, ldc);
            v += bp[col];
            uint16_t h = f2bf(v);
            ((uint16_t*)Cp)[ci] = h;
            // lo term only consumed for q (z==0); k_lo region holds the
            // packed mask bits -- must NOT be written.
            if (z == 0) ((uint16_t*)C2)[ci] = f2bf(v - bf2f(h));
          } else if constexpr (EPI == 1) {
            v += bias[row];
            ((uint16_t*)Cp)[sC * z + toff(row, col, ldc)] = f2bf(v);
          } else if constexpr (EPI == 4) {
            v += resid[(size_t)row * ldc + col];
            ((float*)Cp)[sC * z + (size_t)row * ldc + col] = v;
          } else {  // EPI == 6
            ((uint16_t*)Cp)[sC * z + toff(row, col, ldc)] = f2bf(v * invZ);
          }
        }
      }
    }
  }
}

// ---------------- fp32 [Rx512] row-major -> hi/lo bf16 TILED ---------------
// Core: one block = 16 rows x 128 cols = 2048 elements.
// LDS shuffle -> 16B/lane fully-contiguous stores (R7-proven, ~6.4 TB/s).
__device__ __forceinline__ void split_core(
    const float* __restrict__ x, uint16_t* __restrict__ hi,
    uint16_t* __restrict__ lo, int bid)
{
  __shared__ uint16_t lh[256 * 8 + 16 * 8];   // 16B chunks, 16B pad per 16
  __shared__ uint16_t ll[256 * 8 + 16 * 8];
  const int t   = threadIdx.x;
  const int seg = bid >> 2, q = bid & 3;

  const float* src = x + (size_t)(seg * 16 + (t >> 4)) * 512 + q * 128 + (t & 15) * 8;
  float4 a = *(const float4*)src;
  float4 b = *(const float4*)(src + 4);
  float v[8] = {a.x, a.y, a.z, a.w, b.x, b.y, b.z, b.w};

  const int slot = (t & 15) * 16 + (t >> 4);
  uint16_t* ph = lh + slot * 8 + (slot >> 4) * 8;
  uint16_t* pl = ll + slot * 8 + (slot >> 4) * 8;
#pragma unroll
  for (int e = 0; e < 8; ++e) {
    uint16_t h = f2bf(v[e]);
    ph[e] = h;
    pl[e] = f2bf(v[e] - bf2f(h));
  }
  __syncthreads();

  const uint16_t* qh = lh + t * 8 + (t >> 4) * 8;
  const uint16_t* ql = ll + t * 8 + (t >> 4) * 8;
  const size_t off = (size_t)seg * 8192 + (size_t)(q * 16 + (t >> 4)) * 128 + (t & 15) * 8;
  *(short8*)(hi + off) = *(const short8*)qh;
  *(short8*)(lo + off) = *(const short8*)ql;
}

// enc + emo in one launch: grid 8192 (4096 each)  [R7-proven structure]
__global__ __launch_bounds__(256) void split_pair(
    const float* __restrict__ x0, const float* __restrict__ x1,
    uint16_t* __restrict__ hi, uint16_t* __restrict__ lo, size_t stride)
{
  const int sel = blockIdx.x >> 12;            // 0: enc, 1: emo
  const int bid = blockIdx.x & 4095;
  split_core(sel ? x1 : x0, hi + sel * stride, lo + sel * stride, bid);
}

// 4 weight matrices in one launch: grid 512 (128 each); hi/lo bufs contiguous
__global__ __launch_bounds__(256) void split_w4(
    const float* __restrict__ x0, const float* __restrict__ x1,
    const float* __restrict__ x2, const float* __restrict__ x3,
    uint16_t* __restrict__ hi0, uint16_t* __restrict__ lo0, size_t stride)
{
  const int w   = blockIdx.x >> 7;
  const int bid = blockIdx.x & 127;
  const float* x = (w == 0) ? x0 : (w == 1) ? x1 : (w == 2) ? x2 : x3;
  split_core(x, hi0 + w * stride, lo0 + w * stride, bid);
}

// ---------------- fused LayerNorm epilogue (in-place safe) -----------------
__global__ __launch_bounds__(256) void ln_kernel(
    const float* __restrict__ X, const float* __restrict__ enc,
    const float* __restrict__ gamma, const float* __restrict__ beta,
    float* __restrict__ out)
{
  const int row = blockIdx.x * 4 + (threadIdx.x >> 6);
  const int lane = threadIdx.x & 63;
  const size_t base = (size_t)row * EE;
  const int o0 = lane * 4, o1 = 256 + lane * 4;

  float4 x0 = *(const float4*)(X + base + o0);
  float4 x1 = *(const float4*)(X + base + o1);
  float s = x0.x + x0.y + x0.z + x0.w + x1.x + x1.y + x1.z + x1.w;
#pragma unroll
  for (int off = 32; off > 0; off >>= 1) s += __shfl_xor(s, off);
  const float mean = s * (1.0f / 512.0f);

  float d[8] = {x0.x - mean, x0.y - mean, x0.z - mean, x0.w - mean,
                x1.x - mean, x1.y - mean, x1.z - mean, x1.w - mean};
  float s2 = 0.f;
#pragma unroll
  for (int i = 0; i < 8; ++i) s2 = fmaf(d[i], d[i], s2);
#pragma unroll
  for (int off = 32; off > 0; off >>= 1) s2 += __shfl_xor(s2, off);
  const float stdv = sqrtf(s2 * (1.0f / 512.0f));
  const float inv = 1.0f / (stdv + 1e-6f);

  float4 g0 = *(const float4*)(gamma + o0);
  float4 g1 = *(const float4*)(gamma + o1);
  float4 b0 = *(const float4*)(beta + o0);
  float4 b1 = *(const float4*)(beta + o1);
  float4 e0 = *(const float4*)(enc + base + o0);
  float4 e1 = *(const float4*)(enc + base + o1);

  float4 r0, r1;
  r0.x = e0.x + g0.x * d[0] * inv + b0.x;
  r0.y = e0.y + g0.y * d[1] * inv + b0.y;
  r0.z = e0.z + g0.z * d[2] * inv + b0.z;
  r0.w = e0.w + g0.w * d[3] * inv + b0.w;
  r1.x = e1.x + g1.x * d[4] * inv + b1.x;
  r1.y = e1.y + g1.y * d[5] * inv + b1.y;
  r1.z = e1.z + g1.z * d[6] * inv + b1.z;
  r1.w = e1.w + g1.w * d[7] * inv + b1.w;
  *(float4*)(out + base + o0) = r0;
  *(float4*)(out + base + o1) = r1;
}

extern "C" void kernel_launch(void* const* d_in, const int* in_sizes, int n_in,
                              void* d_out, int out_size, void* d_ws, size_t ws_size,
                              hipStream_t stream) {
  const float* enc   = (const float*)d_in[0];
  const float* emo   = (const float*)d_in[1];
  const int*   mask  = (const int*)d_in[2];
  const float* Wq    = (const float*)d_in[3];
  const float* bq    = (const float*)d_in[4];
  const float* Wk    = (const float*)d_in[5];
  const float* bk    = (const float*)d_in[6];
  const float* Wv    = (const float*)d_in[7];
  const float* bv    = (const float*)d_in[8];
  const float* Wo    = (const float*)d_in[9];
  const float* gamma = (const float*)d_in[10];
  const float* beta  = (const float*)d_in[11];
  float* out = (float*)d_out;
  char*  ws  = (char*)d_ws;

  const size_t SZ = (size_t)BB * SS * EE;   // 8,388,608
  size_t off = 0;
  // adjacency matters: (enc_h,enc_l,emo_h,emo_l) stride 2SZ for fused QK A;
  // (q_hi,q_lo,k_hi,k_lo) stride 2SZ for fused QK C;
  // (wq_h,wq_l,wk_h,wk_l,...) stride 2*EE*EE for fused QK B and split_w4.
  uint16_t* enc_h = (uint16_t*)(ws + off); off += SZ * 2;
  uint16_t* enc_l = (uint16_t*)(ws + off); off += SZ * 2;
  uint16_t* emo_h = (uint16_t*)(ws + off); off += SZ * 2;
  uint16_t* emo_l = (uint16_t*)(ws + off); off += SZ * 2;
  uint16_t* q_hi  = (uint16_t*)(ws + off); off += SZ * 2;
  uint16_t* q_lo  = (uint16_t*)(ws + off); off += SZ * 2;
  uint16_t* k_hi  = (uint16_t*)(ws + off); off += SZ * 2;
  uint16_t* k_lo  = (uint16_t*)(ws + off); off += SZ * 2;  // holds packed mask
  uint16_t* vT    = (uint16_t*)(ws + off); off += SZ * 2;   // [E][B*T] tiled
  uint16_t* ctx   = (uint16_t*)(ws + off); off += SZ * 2;   // [B*S][E] tiled
  uint16_t* wq_h  = (uint16_t*)(ws + off); off += EE * EE * 2;
  uint16_t* wq_l  = (uint16_t*)(ws + off); off += EE * EE * 2;
  uint16_t* wk_h  = (uint16_t*)(ws + off); off += EE * EE * 2;
  uint16_t* wk_l  = (uint16_t*)(ws + off); off += EE * EE * 2;
  uint16_t* wv_h  = (uint16_t*)(ws + off); off += EE * EE * 2;
  uint16_t* wv_l  = (uint16_t*)(ws + off); off += EE * EE * 2;
  uint16_t* wo_h  = (uint16_t*)(ws + off); off += EE * EE * 2;
  uint16_t* wo_l  = (uint16_t*)(ws + off); off += EE * EE * 2;
  uint16_t* P_u   = (uint16_t*)(ws + off); off += (size_t)BB * SS * TT * 2;  // 67MB
  float*    sZ    = (float*)(ws + off);    off += (size_t)BB * SS * 4;
  (void)wk_l; (void)wv_l; (void)wo_l;

  // packed mask bits live in the (otherwise dead) k_lo region: 4.2MB of 16.8MB
  unsigned long long* mbits = (unsigned long long*)k_lo;

  const dim3 blk(256);

  // weights split + enc/emo split (R7-proven LDS-shuffle structure)
  split_w4<<<dim3(512), blk, 0, stream>>>(Wq, Wk, Wv, Wo, wq_h, wq_l,
                                          (size_t)2 * EE * EE);
  split_pair<<<dim3(8192), blk, 0, stream>>>(enc, emo, enc_h, enc_l,
                                             (size_t)2 * SZ);
  hipMemsetAsync(sZ, 0, (size_t)BB * SS * 4, stream);

  // Q,K projections fused (z=0: enc@Wq+bq -> q; z=1: emo@Wk+bk -> k), 3-term
  // + mask ballot-pack under the K-loop (MPK=1): 1024 blk x 16 it x 2 int4
  mgemm<0, 0, 0, 4, 1><<<dim3(4, 128, 2), blk, 0, stream>>>(
      enc_h, enc_l, wq_h, wq_l, q_hi, q_lo, bq, bk, nullptr, mask, nullptr,
      EE, EE, EE, EE, 2 * SZ, (size_t)2 * EE * EE, 2 * SZ, 0, mbits);
  // vT[e][b*T+t] = Wv[e,:].emo[b*T+t,:] + bv[e]   (tiled, ldc = B*T)
  mgemm<1, 1, 1, 4, 0><<<dim3(128, 4, 1), blk, 0, stream>>>(
      wv_h, nullptr, emo_h, nullptr, vT, nullptr, bv, nullptr, nullptr,
      nullptr, nullptr, EE, EE, EE, BB * TT, 0, 0, 0, 0, nullptr);

  // logits 2-term -> masked exp(L-60) bf16 tiled + row sums, all 8 batches
  // (packed mask bits from QK-proj kernel)
  mgemm<0, 1, 5, 4, 0><<<dim3(16, 16, 8), blk, 0, stream>>>(
      q_hi, q_lo, k_hi, nullptr, P_u, nullptr, nullptr, nullptr, nullptr,
      (const int*)mbits, sZ, EE, EE, EE, TT,
      (size_t)SS * EE, (size_t)TT * EE, (size_t)SS * TT, 0, nullptr);

  // ctx = (P_u @ V) / Z, all 8 batches (vT batch-z k-offset = z*T*16 elems)
  mgemm<1, 1, 6, 4, 0><<<dim3(4, 16, 8), blk, 0, stream>>>(
      P_u, nullptr, vT, nullptr, ctx, nullptr, nullptr, nullptr, nullptr,
      nullptr, sZ, TT, TT, BB * TT, EE,
      (size_t)SS * TT, (size_t)TT * 16, (size_t)SS * EE, 0, nullptr);

  // x = enc + ctx @ Wo^T  (fp32 row-major into d_out)
  mgemm<1, 1, 4, 4, 0><<<dim3(4, 128, 1), blk, 0, stream>>>(
      ctx, nullptr, wo_h, nullptr, out, nullptr, nullptr, nullptr, enc,
      nullptr, nullptr, EE, EE, EE, EE, 0, 0, 0, 0, nullptr);
  // out = enc + LN(x), in place
  ln_kernel<<<dim3(BB * SS / 4), blk, 0, stream>>>(out, enc, gamma, beta, out);
}

// Round 10
// 505.199 us; speedup vs baseline: 1.1023x; 1.0315x over previous
//
#include <hip/hip_runtime.h>
#include <math.h>
#include <stdint.h>

// AttnEmo: B=8, S=T=2048, E=512. All-MFMA, fixed-shift unnormalized softmax.
// R17 = R16 resubmitted verbatim (R16's bench died in infra: "container
// failed twice" before any kernel ran; no evidence against the kernel).
// R16 (on R15, 521us):
//  - Wo GEMM + LayerNorm FUSED (wo_ln): session rule "mgemm streams at
//    ~2.6TB/s -> dur ~ bytes" => cut bytes. Old tail: Wo writes X (67MB fp32),
//    ln reads X+enc (134MB), writes out (67MB). New: block = 32 rows x 512
//    cols (full rows in registers), two-pass LN (mean, then sum d^2 -- same
//    order as old ln_kernel) via 16-lane shuffle + cross-wave LDS reduce,
//    writes final out directly. Saves ~200MB. GEMM accumulation sequence per
//    output element identical to old Wo kernel (bit-exact attn path).
// R15: mask ballot-pack rides inside QK-proj GEMM (BW slack there); logits
//    reads 4.2MB packed bits (R12 format, HW-validated).
// Tiled layout: chunk(row,k) at (row>>4)*16*ld + (k>>3)*128 + (row&15)*8+(k&7)
//  -> gld16 staging lane l fetches base+l*16 (1KB contiguous), lands in
//     fragment order, ds_read base+lane*16, zero bank conflicts (R6-proven).

#define BB 8
#define SS 2048
#define TT 2048
#define EE 512

typedef __attribute__((ext_vector_type(8))) short short8;
typedef __attribute__((ext_vector_type(4))) float f32x4;

__device__ __forceinline__ uint16_t f2bf(float f) {      // RNE fp32->bf16
  uint32_t u = __builtin_bit_cast(uint32_t, f);
  u += 0x7fffu + ((u >> 16) & 1u);
  return (uint16_t)(u >> 16);
}
__device__ __forceinline__ float bf2f(uint16_t h) {
  uint32_t u = ((uint32_t)h) << 16;
  return __builtin_bit_cast(float, u);
}

// tiled element offset (ld = row length in elements, multiple of 8)
__device__ __forceinline__ size_t toff(int row, int col, int ld) {
  return (size_t)(row >> 4) * ((size_t)ld << 4) + ((size_t)(col >> 3) << 7)
       + ((row & 15) << 3) + (col & 7);
}

// async global->LDS, 16B per lane; LDS dest = wave-uniform base + lane*16
__device__ __forceinline__ void gld16(const void* g, void* l) {
  __builtin_amdgcn_global_load_lds(
      (const __attribute__((address_space(1))) void*)g,
      (__attribute__((address_space(3))) void*)l, 16, 0, 0);
}

// ---------------------------------------------------------------------------
// NT MFMA GEMM: C[m,n] = sum_k A[m,k]*B[n,k]  (both K-major, TILED layout)
// ASRC: 0 = bf16 hi+lo arrays   1 = bf16 hi only
// BSRC: 0 = bf16 hi+lo arrays   1 = bf16 hi only
//   terms: A0/B0 -> 3 (hh, hl, lh);  A0/B1 -> 2 (hh, lh);  A1/B1 -> 1
// EPI:  0 = +biasz[col], split bf16 out tiled (Cp=hi, C2=lo; lo only z==0)
//       1 = +bias[row], bf16 out tiled                        (vT proj)
//       5 = PACKED mask bits -> P_u=exp(L-60) bf16 tiled + row-sum -> sZ
//       6 = val / sZ[row], bf16 out tiled                     (PV normalize)
// MPK: 1 = also ballot-pack the raw mask into mpk (u64 words) under the
//      K-loop: 2 int4/thread/iter, format = R12 ballot-natural.
// WN: wave n-tiles (4 -> 128-wide block). M-tile = 128. 256 threads.
// ---------------------------------------------------------------------------
template<int ASRC, int BSRC, int EPI, int WN, int MPK>
__global__ __launch_bounds__(256, 2) void mgemm(
    const void* __restrict__ Ap, const void* __restrict__ Alo,
    const void* __restrict__ Bp, const void* __restrict__ Blo,
    void* __restrict__ Cp, void* __restrict__ C2,
    const float* __restrict__ bias, const float* __restrict__ bias2,
    const float* __restrict__ resid,
    const int* __restrict__ mask, float* __restrict__ sZ,
    int K, int lda, int ldb, int ldc,
    size_t sA, size_t sB, size_t sC, size_t sM,
    unsigned long long* __restrict__ mpk)
{
  constexpr bool ALOARR = (ASRC == 0);
  constexpr bool BLOARR = (BSRC == 0);
  constexpr bool T3     = (ASRC == 0) && (BSRC == 0);
  constexpr bool T2     = (ASRC == 0) && (BSRC == 1);
  constexpr int  BN     = 32 * WN;
  constexpr int  ABYTES = ALOARR ? 16384 : 8192;
  constexpr int  BBYTES = BLOARR ? BN * 128 : BN * 64;

  __shared__ char smem[ABYTES + BBYTES];

  const int tid  = threadIdx.x;
  const int lane = tid & 63, wv = tid >> 6;
  const int z    = blockIdx.z;
  const int bm   = blockIdx.y * 128;
  const int bn   = blockIdx.x * BN;
  const int fr   = lane & 15;            // fragment row/col
  const int wm   = (wv & 1) * 64;
  const int wn   = (wv >> 1) * (16 * WN);

  const f32x4 zero = {0.f, 0.f, 0.f, 0.f};
  f32x4 acc[4][WN];
#pragma unroll
  for (int i = 0; i < 4; ++i)
#pragma unroll
    for (int j = 0; j < WN; ++j) acc[i][j] = zero;

  // tiled layout: staging lane l's offset within a (16-row x 32-k) seg-tile
  // is just l*8 elements (l*16 bytes) -- fully contiguous per gld16.
  const size_t loff = (size_t)lane * 8;
  const uint16_t* gAh = (const uint16_t*)Ap + sA * z + (size_t)(bm >> 4) * 16 * lda + loff;
  const uint16_t* gAl = ALOARR ? (const uint16_t*)Alo + sA * z + (size_t)(bm >> 4) * 16 * lda + loff : nullptr;
  const uint16_t* gBh = (const uint16_t*)Bp + sB * z + (size_t)(bn >> 4) * 16 * ldb + loff;
  const uint16_t* gBl = BLOARR ? (const uint16_t*)Blo + sB * z + (size_t)(bn >> 4) * 16 * ldb + loff : nullptr;

  // MPK: flat block id -> this block's 128-group span of the mask
  const int mflat = MPK ? (blockIdx.x + gridDim.x * (blockIdx.y + gridDim.y * blockIdx.z)) : 0;

  for (int k0 = 0; k0 < K; k0 += 32) {
    const size_t ka = (size_t)k0 * 16;           // (k0>>3)*128 elements
    const int r = k0 >> 5;                       // K-iteration index
    __syncthreads();                       // previous tiles fully consumed
    // ---- stage A (8 segs x 1KB each) ----
#pragma unroll
    for (int t = 0; t < 2; ++t) { int s = wv + t * 4;
      gld16(gAh + (size_t)s * 16 * lda + ka, &smem[s * 1024]); }
    if constexpr (ALOARR) {
#pragma unroll
      for (int t = 0; t < 2; ++t) { int s = wv + t * 4;
        gld16(gAl + (size_t)s * 16 * lda + ka, &smem[8192 + s * 1024]); }
    }
    // ---- stage B ----
#pragma unroll
    for (int t = 0; t < WN / 2; ++t) { int s = wv + t * 4;
      gld16(gBh + (size_t)s * 16 * ldb + ka, &smem[ABYTES + s * 1024]); }
    if constexpr (BLOARR) {
#pragma unroll
      for (int t = 0; t < WN / 2; ++t) { int s = wv + t * 4;
        gld16(gBl + (size_t)s * 16 * ldb + ka, &smem[ABYTES + BN * 64 + s * 1024]); }
    }
    // ---- MPK: this iteration's 2 mask int4 ride with the staging ----
    int4 mq0, mq1; int Gg0 = 0;
    if constexpr (MPK) {
      Gg0 = mflat * 128 + r * 8 + wv * 2;        // 2 groups per wave per iter
      mq0 = ((const int4*)mask)[(size_t)Gg0 * 64 + lane];
      mq1 = ((const int4*)mask)[(size_t)(Gg0 + 1) * 64 + lane];
    }
    __syncthreads();                       // staging (and mq) landed

    // ---- fragments: each wave reads base + lane*16 (conflict-free) ----
    short8 ah[4], bh[WN], al_[4], bl_[WN];
#pragma unroll
    for (int i = 0; i < 4; ++i) {
      const char* p = smem + ((wm >> 4) + i) * 1024 + (lane << 4);
      ah[i] = *(const short8*)p;
      if constexpr (ALOARR) al_[i] = *(const short8*)(p + 8192);
    }
#pragma unroll
    for (int j = 0; j < WN; ++j) {
      const char* p = smem + ABYTES + ((wn >> 4) + j) * 1024 + (lane << 4);
      bh[j] = *(const short8*)p;
      if constexpr (BLOARR) bl_[j] = *(const short8*)(p + BN * 64);
    }
    // ---- MFMA ----
#pragma unroll
    for (int i = 0; i < 4; ++i)
#pragma unroll
      for (int j = 0; j < WN; ++j) {
        acc[i][j] = __builtin_amdgcn_mfma_f32_16x16x32_bf16(ah[i], bh[j], acc[i][j], 0, 0, 0);
        if constexpr (T3) {
          acc[i][j] = __builtin_amdgcn_mfma_f32_16x16x32_bf16(ah[i], bl_[j], acc[i][j], 0, 0, 0);
          acc[i][j] = __builtin_amdgcn_mfma_f32_16x16x32_bf16(al_[i], bh[j], acc[i][j], 0, 0, 0);
        } else if constexpr (T2) {
          acc[i][j] = __builtin_amdgcn_mfma_f32_16x16x32_bf16(al_[i], bh[j], acc[i][j], 0, 0, 0);
        }
      }

    // ---- MPK: ballots + store AFTER the MFMAs (no issue stall) ----
    if constexpr (MPK) {
#pragma unroll
      for (int p = 0; p < 2; ++p) {
        const int4 m = p ? mq1 : mq0;
        const unsigned long long b0 = __ballot(m.x != 0);
        const unsigned long long b1 = __ballot(m.y != 0);
        const unsigned long long b2 = __ballot(m.z != 0);
        const unsigned long long b3 = __ballot(m.w != 0);
        if (lane < 4) {
          const unsigned long long w64 = (lane == 0) ? b0 : (lane == 1) ? b1
                                       : (lane == 2) ? b2 : b3;
          mpk[(size_t)(Gg0 + p) * 4 + lane] = w64;
        }
      }
    }
  }

  // ---- epilogue: C/D layout col=lane&15, row=(lane>>4)*4+reg ----
  if constexpr (EPI == 5) {
    // mask = PACKED BITS (R12 format, HW-validated): for 256-int group G,
    // word G*4+j bit l = int G*256+4l+j. For this wave's span c0 = bn+wn:
    //   word = z*65536 + (c0>>8)*4 + (fr&3) + row*32
    //   bit  = ((c0&255)>>2) + (fr>>2) + j*4
    const unsigned long long* __restrict__ mb = (const unsigned long long*)mask;
    const int c0 = bn + wn;
    const int sh = ((c0 & 255) >> 2) + (fr >> 2);
    const size_t mbase = (size_t)z * 65536 + (size_t)((c0 >> 8) << 2) + (fr & 3);
    unsigned long long mw[4][4];
#pragma unroll
    for (int i = 0; i < 4; ++i)
#pragma unroll
      for (int g = 0; g < 4; ++g) {
        const int row = bm + wm + i * 16 + (lane >> 4) * 4 + g;
        mw[i][g] = mb[mbase + (size_t)row * 32];
      }
#pragma unroll
    for (int i = 0; i < 4; ++i) {
      const int row0 = bm + wm + i * 16 + (lane >> 4) * 4;
#pragma unroll
      for (int g = 0; g < 4; ++g) {
        const int row = row0 + g;
        float rs = 0.f;
#pragma unroll
        for (int j = 0; j < WN; ++j) {
          const int col = bn + wn + j * 16 + fr;
          const bool msk = (mw[i][g] >> (sh + j * 4)) & 1ull;
          const float e = msk ? 0.f : __expf(acc[i][j][g] - 60.0f);
          ((uint16_t*)Cp)[sC * z + toff(row, col, ldc)] = f2bf(e);
          rs += e;
        }
        rs += __shfl_xor(rs, 1);
        rs += __shfl_xor(rs, 2);
        rs += __shfl_xor(rs, 4);
        rs += __shfl_xor(rs, 8);
        if ((lane & 15) == 0) atomicAdd(&sZ[(size_t)z * SS + row], rs);
      }
    }
  } else {
#pragma unroll
    for (int i = 0; i < 4; ++i) {
      const int row0 = bm + wm + i * 16 + (lane >> 4) * 4;
#pragma unroll
      for (int g = 0; g < 4; ++g) {
        const int row = row0 + g;
        float invZ = 1.0f;
        if constexpr (EPI == 6) invZ = 1.0f / sZ[(size_t)z * SS + row];
#pragma unroll
        for (int j = 0; j < WN; ++j) {
          const int col = bn + wn + j * 16 + fr;
          float v = acc[i][j][g];
          if constexpr (EPI == 0) {
            const float* bp = (z == 0) ? bias : bias2;
            const size_t ci = sC * z + toff(row, col, ldc);
            v += bp[col];
            uint16_t h = f2bf(v);
            ((uint16_t*)Cp)[ci] = h;
            // lo term only consumed for q (z==0); k_lo region holds the
            // packed mask bits -- must NOT be written.
            if (z == 0) ((uint16_t*)C2)[ci] = f2bf(v - bf2f(h));
          } else if constexpr (EPI == 1) {
            v += bias[row];
            ((uint16_t*)Cp)[sC * z + toff(row, col, ldc)] = f2bf(v);
          } else {  // EPI == 6
            ((uint16_t*)Cp)[sC * z + toff(row, col, ldc)] = f2bf(v * invZ);
          }
        }
      }
    }
  }
}

// ---------------------------------------------------------------------------
// Fused Wo-projection + residual + LayerNorm + residual.
// Block = 32 rows x 512 cols (FULL rows in registers), grid 512, 4 waves.
// Wave w: cols [w*128, w*128+128), rows 0..31 -> acc[2][8] f32x4.
// x = enc + ctx@Wo^T;  out = enc + gamma*(x-mean)/(std+eps) + beta.
// Two-pass LN (mean, then sum of squared dev) via 16-lane shuffle +
// cross-wave LDS reduce -- same math order as the old ln_kernel.
// ---------------------------------------------------------------------------
__global__ __launch_bounds__(256, 2) void wo_ln(
    const uint16_t* __restrict__ ctx, const uint16_t* __restrict__ woh,
    const float* __restrict__ enc, const float* __restrict__ gamma,
    const float* __restrict__ beta, float* __restrict__ out)
{
  constexpr int ABYTES = 2048;                 // 2 A-segs (32 rows x 32 k)
  __shared__ char smem[ABYTES + 32768];        // + 32 B-segs (512 cols x 32 k)
  __shared__ float red[4][32];

  const int tid  = threadIdx.x;
  const int lane = tid & 63, wv = tid >> 6;
  const int R0   = blockIdx.x * 32;
  const int fr   = lane & 15;
  const int wn   = wv * 128;

  const f32x4 zero = {0.f, 0.f, 0.f, 0.f};
  f32x4 acc[2][8];
#pragma unroll
  for (int i = 0; i < 2; ++i)
#pragma unroll
    for (int j = 0; j < 8; ++j) acc[i][j] = zero;

  const size_t loff = (size_t)lane * 8;
  const uint16_t* gA = ctx + (size_t)(R0 >> 4) * 8192 + loff;
  const uint16_t* gB = woh + loff;

  for (int k0 = 0; k0 < EE; k0 += 32) {
    const size_t ka = (size_t)k0 * 16;
    __syncthreads();
    if (wv < 2)
      gld16(gA + (size_t)wv * 8192 + ka, &smem[wv * 1024]);
#pragma unroll
    for (int t = 0; t < 8; ++t) { const int s = wv + t * 4;
      gld16(gB + (size_t)s * 8192 + ka, &smem[ABYTES + s * 1024]); }
    __syncthreads();

    short8 a0 = *(const short8*)(smem + (lane << 4));
    short8 a1 = *(const short8*)(smem + 1024 + (lane << 4));
    short8 b[8];
#pragma unroll
    for (int j = 0; j < 8; ++j)
      b[j] = *(const short8*)(smem + ABYTES + (wv * 8 + j) * 1024 + (lane << 4));
#pragma unroll
    for (int j = 0; j < 8; ++j) {
      acc[0][j] = __builtin_amdgcn_mfma_f32_16x16x32_bf16(a0, b[j], acc[0][j], 0, 0, 0);
      acc[1][j] = __builtin_amdgcn_mfma_f32_16x16x32_bf16(a1, b[j], acc[1][j], 0, 0, 0);
    }
  }

  // ---- epilogue: full rows resident -> fused residual + LayerNorm ----
  // C/D layout: col = wn + j*16 + fr, row = R0 + i*16 + (lane>>4)*4 + g.
  float e[2][8][4];
#pragma unroll
  for (int i = 0; i < 2; ++i)
#pragma unroll
    for (int g = 0; g < 4; ++g) {
      const int row = R0 + i * 16 + ((lane >> 4) << 2) + g;
#pragma unroll
      for (int j = 0; j < 8; ++j)
        e[i][j][g] = enc[(size_t)row * EE + wn + j * 16 + fr];
    }

  // pass 1: mean
  float mn[2][4];
#pragma unroll
  for (int i = 0; i < 2; ++i)
#pragma unroll
    for (int g = 0; g < 4; ++g) {
      float s = 0.f;
#pragma unroll
      for (int j = 0; j < 8; ++j) s += acc[i][j][g] + e[i][j][g];
      s += __shfl_xor(s, 1); s += __shfl_xor(s, 2);
      s += __shfl_xor(s, 4); s += __shfl_xor(s, 8);
      if (fr == 0) red[wv][i * 16 + ((lane >> 4) << 2) + g] = s;
    }
  __syncthreads();
#pragma unroll
  for (int i = 0; i < 2; ++i)
#pragma unroll
    for (int g = 0; g < 4; ++g) {
      const int lr = i * 16 + ((lane >> 4) << 2) + g;
      mn[i][g] = (red[0][lr] + red[1][lr] + red[2][lr] + red[3][lr])
               * (1.0f / 512.0f);
    }
  __syncthreads();

  // pass 2: variance (sum of squared deviations)
  float iv[2][4];
#pragma unroll
  for (int i = 0; i < 2; ++i)
#pragma unroll
    for (int g = 0; g < 4; ++g) {
      float s2 = 0.f;
#pragma unroll
      for (int j = 0; j < 8; ++j) {
        const float d = acc[i][j][g] + e[i][j][g] - mn[i][g];
        s2 = fmaf(d, d, s2);
      }
      s2 += __shfl_xor(s2, 1); s2 += __shfl_xor(s2, 2);
      s2 += __shfl_xor(s2, 4); s2 += __shfl_xor(s2, 8);
      if (fr == 0) red[wv][i * 16 + ((lane >> 4) << 2) + g] = s2;
    }
  __syncthreads();
#pragma unroll
  for (int i = 0; i < 2; ++i)
#pragma unroll
    for (int g = 0; g < 4; ++g) {
      const int lr = i * 16 + ((lane >> 4) << 2) + g;
      const float var = (red[0][lr] + red[1][lr] + red[2][lr] + red[3][lr])
                      * (1.0f / 512.0f);
      iv[i][g] = 1.0f / (sqrtf(var) + 1e-6f);
    }

  float gm[8], bt[8];
#pragma unroll
  for (int j = 0; j < 8; ++j) {
    gm[j] = gamma[wn + j * 16 + fr];
    bt[j] = beta[wn + j * 16 + fr];
  }
#pragma unroll
  for (int i = 0; i < 2; ++i)
#pragma unroll
    for (int g = 0; g < 4; ++g) {
      const int row = R0 + i * 16 + ((lane >> 4) << 2) + g;
      const float m = mn[i][g], v_inv = iv[i][g];
#pragma unroll
      for (int j = 0; j < 8; ++j) {
        const float v = acc[i][j][g] + e[i][j][g];
        out[(size_t)row * EE + wn + j * 16 + fr] =
            e[i][j][g] + gm[j] * (v - m) * v_inv + bt[j];
      }
    }
}

// ---------------- fp32 [Rx512] row-major -> hi/lo bf16 TILED ---------------
// Core: one block = 16 rows x 128 cols = 2048 elements.
// LDS shuffle -> 16B/lane fully-contiguous stores (R7-proven, ~6.4 TB/s).
__device__ __forceinline__ void split_core(
    const float* __restrict__ x, uint16_t* __restrict__ hi,
    uint16_t* __restrict__ lo, int bid)
{
  __shared__ uint16_t lh[256 * 8 + 16 * 8];   // 16B chunks, 16B pad per 16
  __shared__ uint16_t ll[256 * 8 + 16 * 8];
  const int t   = threadIdx.x;
  const int seg = bid >> 2, q = bid & 3;

  const float* src = x + (size_t)(seg * 16 + (t >> 4)) * 512 + q * 128 + (t & 15) * 8;
  float4 a = *(const float4*)src;
  float4 b = *(const float4*)(src + 4);
  float v[8] = {a.x, a.y, a.z, a.w, b.x, b.y, b.z, b.w};

  const int slot = (t & 15) * 16 + (t >> 4);
  uint16_t* ph = lh + slot * 8 + (slot >> 4) * 8;
  uint16_t* pl = ll + slot * 8 + (slot >> 4) * 8;
#pragma unroll
  for (int e = 0; e < 8; ++e) {
    uint16_t h = f2bf(v[e]);
    ph[e] = h;
    pl[e] = f2bf(v[e] - bf2f(h));
  }
  __syncthreads();

  const uint16_t* qh = lh + t * 8 + (t >> 4) * 8;
  const uint16_t* ql = ll + t * 8 + (t >> 4) * 8;
  const size_t off = (size_t)seg * 8192 + (size_t)(q * 16 + (t >> 4)) * 128 + (t & 15) * 8;
  *(short8*)(hi + off) = *(const short8*)qh;
  *(short8*)(lo + off) = *(const short8*)ql;
}

// enc + emo in one launch: grid 8192 (4096 each)  [R7-proven structure]
__global__ __launch_bounds__(256) void split_pair(
    const float* __restrict__ x0, const float* __restrict__ x1,
    uint16_t* __restrict__ hi, uint16_t* __restrict__ lo, size_t stride)
{
  const int sel = blockIdx.x >> 12;            // 0: enc, 1: emo
  const int bid = blockIdx.x & 4095;
  split_core(sel ? x1 : x0, hi + sel * stride, lo + sel * stride, bid);
}

// 4 weight matrices in one launch: grid 512 (128 each); hi/lo bufs contiguous
__global__ __launch_bounds__(256) void split_w4(
    const float* __restrict__ x0, const float* __restrict__ x1,
    const float* __restrict__ x2, const float* __restrict__ x3,
    uint16_t* __restrict__ hi0, uint16_t* __restrict__ lo0, size_t stride)
{
  const int w   = blockIdx.x >> 7;
  const int bid = blockIdx.x & 127;
  const float* x = (w == 0) ? x0 : (w == 1) ? x1 : (w == 2) ? x2 : x3;
  split_core(x, hi0 + w * stride, lo0 + w * stride, bid);
}

extern "C" void kernel_launch(void* const* d_in, const int* in_sizes, int n_in,
                              void* d_out, int out_size, void* d_ws, size_t ws_size,
                              hipStream_t stream) {
  const float* enc   = (const float*)d_in[0];
  const float* emo   = (const float*)d_in[1];
  const int*   mask  = (const int*)d_in[2];
  const float* Wq    = (const float*)d_in[3];
  const float* bq    = (const float*)d_in[4];
  const float* Wk    = (const float*)d_in[5];
  const float* bk    = (const float*)d_in[6];
  const float* Wv    = (const float*)d_in[7];
  const float* bv    = (const float*)d_in[8];
  const float* Wo    = (const float*)d_in[9];
  const float* gamma = (const float*)d_in[10];
  const float* beta  = (const float*)d_in[11];
  float* out = (float*)d_out;
  char*  ws  = (char*)d_ws;

  const size_t SZ = (size_t)BB * SS * EE;   // 8,388,608
  size_t off = 0;
  // adjacency matters: (enc_h,enc_l,emo_h,emo_l) stride 2SZ for fused QK A;
  // (q_hi,q_lo,k_hi,k_lo) stride 2SZ for fused QK C;
  // (wq_h,wq_l,wk_h,wk_l,...) stride 2*EE*EE for fused QK B and split_w4.
  uint16_t* enc_h = (uint16_t*)(ws + off); off += SZ * 2;
  uint16_t* enc_l = (uint16_t*)(ws + off); off += SZ * 2;
  uint16_t* emo_h = (uint16_t*)(ws + off); off += SZ * 2;
  uint16_t* emo_l = (uint16_t*)(ws + off); off += SZ * 2;
  uint16_t* q_hi  = (uint16_t*)(ws + off); off += SZ * 2;
  uint16_t* q_lo  = (uint16_t*)(ws + off); off += SZ * 2;
  uint16_t* k_hi  = (uint16_t*)(ws + off); off += SZ * 2;
  uint16_t* k_lo  = (uint16_t*)(ws + off); off += SZ * 2;  // holds packed mask
  uint16_t* vT    = (uint16_t*)(ws + off); off += SZ * 2;   // [E][B*T] tiled
  uint16_t* ctx   = (uint16_t*)(ws + off); off += SZ * 2;   // [B*S][E] tiled
  uint16_t* wq_h  = (uint16_t*)(ws + off); off += EE * EE * 2;
  uint16_t* wq_l  = (uint16_t*)(ws + off); off += EE * EE * 2;
  uint16_t* wk_h  = (uint16_t*)(ws + off); off += EE * EE * 2;
  uint16_t* wk_l  = (uint16_t*)(ws + off); off += EE * EE * 2;
  uint16_t* wv_h  = (uint16_t*)(ws + off); off += EE * EE * 2;
  uint16_t* wv_l  = (uint16_t*)(ws + off); off += EE * EE * 2;
  uint16_t* wo_h  = (uint16_t*)(ws + off); off += EE * EE * 2;
  uint16_t* wo_l  = (uint16_t*)(ws + off); off += EE * EE * 2;
  uint16_t* P_u   = (uint16_t*)(ws + off); off += (size_t)BB * SS * TT * 2;  // 67MB
  float*    sZ    = (float*)(ws + off);    off += (size_t)BB * SS * 4;
  (void)wk_l; (void)wv_l; (void)wo_l;

  // packed mask bits live in the (otherwise dead) k_lo region: 4.2MB of 16.8MB
  unsigned long long* mbits = (unsigned long long*)k_lo;

  const dim3 blk(256);

  // weights split + enc/emo split (R7-proven LDS-shuffle structure)
  split_w4<<<dim3(512), blk, 0, stream>>>(Wq, Wk, Wv, Wo, wq_h, wq_l,
                                          (size_t)2 * EE * EE);
  split_pair<<<dim3(8192), blk, 0, stream>>>(enc, emo, enc_h, enc_l,
                                             (size_t)2 * SZ);
  hipMemsetAsync(sZ, 0, (size_t)BB * SS * 4, stream);

  // Q,K projections fused (z=0: enc@Wq+bq -> q; z=1: emo@Wk+bk -> k), 3-term
  // + mask ballot-pack under the K-loop (MPK=1): 1024 blk x 16 it x 2 int4
  mgemm<0, 0, 0, 4, 1><<<dim3(4, 128, 2), blk, 0, stream>>>(
      enc_h, enc_l, wq_h, wq_l, q_hi, q_lo, bq, bk, nullptr, mask, nullptr,
      EE, EE, EE, EE, 2 * SZ, (size_t)2 * EE * EE, 2 * SZ, 0, mbits);
  // vT[e][b*T+t] = Wv[e,:].emo[b*T+t,:] + bv[e]   (tiled, ldc = B*T)
  mgemm<1, 1, 1, 4, 0><<<dim3(128, 4, 1), blk, 0, stream>>>(
      wv_h, nullptr, emo_h, nullptr, vT, nullptr, bv, nullptr, nullptr,
      nullptr, nullptr, EE, EE, EE, BB * TT, 0, 0, 0, 0, nullptr);

  // logits 2-term -> masked exp(L-60) bf16 tiled + row sums, all 8 batches
  // (packed mask bits from QK-proj kernel)
  mgemm<0, 1, 5, 4, 0><<<dim3(16, 16, 8), blk, 0, stream>>>(
      q_hi, q_lo, k_hi, nullptr, P_u, nullptr, nullptr, nullptr, nullptr,
      (const int*)mbits, sZ, EE, EE, EE, TT,
      (size_t)SS * EE, (size_t)TT * EE, (size_t)SS * TT, 0, nullptr);

  // ctx = (P_u @ V) / Z, all 8 batches (vT batch-z k-offset = z*T*16 elems)
  mgemm<1, 1, 6, 4, 0><<<dim3(4, 16, 8), blk, 0, stream>>>(
      P_u, nullptr, vT, nullptr, ctx, nullptr, nullptr, nullptr, nullptr,
      nullptr, sZ, TT, TT, BB * TT, EE,
      (size_t)SS * TT, (size_t)TT * 16, (size_t)SS * EE, 0, nullptr);

  // out = enc + LN(enc + ctx @ Wo^T)  -- fused, single pass
  wo_ln<<<dim3(BB * SS / 32), blk, 0, stream>>>(ctx, wo_h, enc, gamma, beta, out);
}